// Round 5
// baseline (4390.871 us; speedup 1.0000x reference)
//
#include <hip/hip_runtime.h>
#include <cstdint>
#include <cstddef>

constexpr int Tn = 12, Bn = 16, Nn = 1024, Hn = 64, Ln = 2;
constexpr int ROWS = Bn * Nn;                 // 16384
constexpr int TOT  = Tn * Bn * Nn;            // 196608
constexpr int HALF = TOT / 2;
constexpr size_t HSZ = (size_t)Bn * Nn * Hn;  // 1048576 floats

#define DEVFN __device__ __forceinline__

typedef __attribute__((ext_vector_type(4))) float f32x4;
typedef __attribute__((ext_vector_type(8))) __bf16 bf16x8;
typedef unsigned short ushort_t;

// weight-plane offsets (in elements) inside WH/WL
constexpr size_t WOFF_PZ = 0;        // [d][l][n:128][k:128]  prez B
constexpr size_t WOFF_PC = 65536;    // [d][l][n:64][k:128]   prec B
constexpr size_t WOFF_P2 = 98304;    // [n:64][k:256]         proj B (Wp2)
constexpr size_t WOFF_D1 = 114688;   // [n:256][k:128]        dec1 B (Wd1)
constexpr size_t WOFF_D2 = 147456;   // [n:64][k:256]         dec2 B (Wd2)
constexpr size_t WTOT    = 163840;

// ---------------------------------------------------------------------------
// bf16 split helpers (RNE)
// ---------------------------------------------------------------------------
DEVFN ushort_t f2bf_rne(float f) {
  uint32_t u = __float_as_uint(f);
  uint32_t r = u + 0x7FFFu + ((u >> 16) & 1u);
  return (ushort_t)(r >> 16);
}
DEVFN float bf2f(ushort_t h) { return __uint_as_float(((uint32_t)h) << 16); }

DEVFN void split8(const float* f, bf16x8& h8, bf16x8& l8) {
  alignas(16) ushort_t hs[8], ls[8];
#pragma unroll
  for (int j = 0; j < 8; ++j) {
    ushort_t h = f2bf_rne(f[j]);
    hs[j] = h;
    ls[j] = f2bf_rne(f[j] - bf2f(h));
  }
  h8 = *reinterpret_cast<bf16x8*>(hs);
  l8 = *reinterpret_cast<bf16x8*>(ls);
}

DEVFN f32x4 mm3(bf16x8 ah, bf16x8 al, bf16x8 bh, bf16x8 bl, f32x4 c) {
  c = __builtin_amdgcn_mfma_f32_16x16x32_bf16(ah, bh, c, 0, 0, 0);
  c = __builtin_amdgcn_mfma_f32_16x16x32_bf16(ah, bl, c, 0, 0, 0);
  c = __builtin_amdgcn_mfma_f32_16x16x32_bf16(al, bh, c, 0, 0, 0);
  return c;
}

DEVFN bf16x8 ld16(const ushort_t* p) { return *reinterpret_cast<const bf16x8*>(p); }

DEVFN void ld8f(const float* p, float* out) {
  float4 v0 = *reinterpret_cast<const float4*>(p);
  float4 v1 = *reinterpret_cast<const float4*>(p + 4);
  out[0] = v0.x; out[1] = v0.y; out[2] = v0.z; out[3] = v0.w;
  out[4] = v1.x; out[5] = v1.y; out[6] = v1.z; out[7] = v1.w;
}

// ---------------------------------------------------------------------------
// threefry2x32 (key 0,42) + XLA-exact normal
// ---------------------------------------------------------------------------
DEVFN uint32_t rotl32(uint32_t v, int d) { return (v << d) | (v >> (32 - d)); }

DEVFN void threefry_0_42(uint32_t& x0, uint32_t& x1) {
  const uint32_t k0 = 0u, k1 = 42u, k2 = k0 ^ k1 ^ 0x1BD11BDAu;
  x0 += k0; x1 += k1;
#define TFR(r) { x0 += x1; x1 = rotl32(x1, r); x1 ^= x0; }
  TFR(13) TFR(15) TFR(26) TFR(6)
  x0 += k1; x1 += k2 + 1u;
  TFR(17) TFR(29) TFR(16) TFR(24)
  x0 += k2; x1 += k0 + 2u;
  TFR(13) TFR(15) TFR(26) TFR(6)
  x0 += k0; x1 += k1 + 3u;
  TFR(17) TFR(29) TFR(16) TFR(24)
  x0 += k1; x1 += k2 + 4u;
  TFR(13) TFR(15) TFR(26) TFR(6)
  x0 += k2; x1 += k0 + 5u;
#undef TFR
}

DEVFN float erfinv32(float x) {
  float w = -log1pf(-x * x);
  float p;
  if (w < 5.0f) {
    w = w - 2.5f;
    p = 2.81022636e-08f;
    p = fmaf(p, w, 3.43273939e-07f);
    p = fmaf(p, w, -3.5233877e-06f);
    p = fmaf(p, w, -4.39150654e-06f);
    p = fmaf(p, w, 0.00021858087f);
    p = fmaf(p, w, -0.00125372503f);
    p = fmaf(p, w, -0.00417768164f);
    p = fmaf(p, w, 0.246640727f);
    p = fmaf(p, w, 1.50140941f);
  } else {
    w = sqrtf(w) - 3.0f;
    p = -0.000200214257f;
    p = fmaf(p, w, 0.000100950558f);
    p = fmaf(p, w, 0.00134934322f);
    p = fmaf(p, w, -0.00367342844f);
    p = fmaf(p, w, 0.00573950773f);
    p = fmaf(p, w, -0.0076224613f);
    p = fmaf(p, w, 0.00943887047f);
    p = fmaf(p, w, 1.00167406f);
    p = fmaf(p, w, 2.83297682f);
  }
  return p * x;
}

DEVFN float bits_to_normal(uint32_t bits) {
  float f = __uint_as_float((bits >> 9) | 0x3f800000u) - 1.0f;
  const float lo = -0.99999994f;
  float u = fmaf(f, 2.0f, lo);
  u = fmaxf(lo, u);
  return 1.41421356237f * erfinv32(u);
}

__global__ __launch_bounds__(256) void seq_kernel(const float* __restrict__ inputs,
                                                  float* __restrict__ s0) {
  int i = blockIdx.x * 256 + threadIdx.x;
  if (i >= HALF) return;
  uint32_t x0 = (uint32_t)i, x1 = (uint32_t)(i + HALF);
  threefry_0_42(x0, x1);
  s0[i]        = inputs[i]        + 0.01f * bits_to_normal(x0);
  s0[i + HALF] = inputs[i + HALF] + 0.01f * bits_to_normal(x1);
}

DEVFN float sigmoidf_(float x) { return 1.0f / (1.0f + expf(-x)); }

// ---------------------------------------------------------------------------
// adj -> bf16 hi/lo planes
// ---------------------------------------------------------------------------
__global__ __launch_bounds__(256) void adjsplit_kernel(const float* __restrict__ adj,
                                                       ushort_t* __restrict__ hi,
                                                       ushort_t* __restrict__ lo) {
  int i = blockIdx.x * 256 + threadIdx.x;
  float v = adj[i];
  ushort_t h = f2bf_rne(v);
  hi[i] = h;
  lo[i] = f2bf_rne(v - bf2f(h));
}

// ---------------------------------------------------------------------------
// wprep: split + transpose all GEMM B-weights into [n][k] bf16 hi/lo planes
// ---------------------------------------------------------------------------
__global__ __launch_bounds__(256) void wprep_kernel(
    const float* __restrict__ WzF, const float* __restrict__ WrF, const float* __restrict__ WcF,
    const float* __restrict__ WzR, const float* __restrict__ WrR, const float* __restrict__ WcR,
    const float* __restrict__ Wp2, const float* __restrict__ Wd1, const float* __restrict__ Wd2,
    ushort_t* __restrict__ WH, ushort_t* __restrict__ WL)
{
  size_t i = (size_t)blockIdx.x * 256 + threadIdx.x;
  if (i >= WTOT) return;
  float v;
  if (i < WOFF_PC) {                          // PZ [d][l][n:128][k:128]
    int d = (i >> 15) & 1, l = (i >> 14) & 1, n = (i >> 7) & 127, k = i & 127;
    const float* W = (n < 64) ? (d ? WzR : WzF) : (d ? WrR : WrF);
    v = W[l * 8192 + k * 64 + (n & 63)];
  } else if (i < WOFF_P2) {                   // PC [d][l][n:64][k:128]
    size_t j = i - WOFF_PC;
    int d = (j >> 14) & 1, l = (j >> 13) & 1, n = (j >> 7) & 63, k = j & 127;
    const float* W = d ? WcR : WcF;
    v = W[l * 8192 + k * 64 + n];
  } else if (i < WOFF_D1) {                   // P2 [n:64][k:256]
    size_t j = i - WOFF_P2;
    int n = j >> 8, k = j & 255;
    v = Wp2[k * 64 + n];
  } else if (i < WOFF_D2) {                   // D1 [n:256][k:128]
    size_t j = i - WOFF_D1;
    int n = j >> 7, k = j & 127;
    v = Wd1[k * 256 + n];
  } else {                                    // D2 [n:64][k:256]
    size_t j = i - WOFF_D2;
    int n = j >> 8, k = j & 255;
    v = Wd2[k * 64 + n];
  }
  ushort_t h = f2bf_rne(v);
  WH[i] = h;
  WL[i] = f2bf_rne(v - bf2f(h));
}

// ---------------------------------------------------------------------------
// proj: X[m][64] = relu(s0*W0+s1*W1+bp1) @ Wp2 + bp2   (M=196608,N=64,K=256)
// ---------------------------------------------------------------------------
__global__ __launch_bounds__(256) void proj_mfma(
    const float* __restrict__ s0g, const float* __restrict__ s1g,
    const float* __restrict__ Wp1, const float* __restrict__ bp1,
    const float* __restrict__ bp2,
    const ushort_t* __restrict__ WH, const ushort_t* __restrict__ WL,
    float* __restrict__ X)
{
  __shared__ float W0[256], W1[256], Bb[256], SS0[256], SS1[256];
  const int tid = threadIdx.x;
  const int row0 = blockIdx.x * 256;
  W0[tid] = Wp1[tid];
  W1[tid] = Wp1[256 + tid];
  Bb[tid] = bp1[tid];
  SS0[tid] = s0g[row0 + tid];
  SS1[tid] = s1g[row0 + tid];
  __syncthreads();

  const int lane = tid & 63, wave = tid >> 6;
  const int lm = lane & 15, q8 = (lane >> 4) * 8;
  const ushort_t* P2H = WH + WOFF_P2;
  const ushort_t* P2L = WL + WOFF_P2;

  float sv0[4], sv1[4];
#pragma unroll
  for (int ti = 0; ti < 4; ++ti) {
    sv0[ti] = SS0[wave * 64 + ti * 16 + lm];
    sv1[ti] = SS1[wave * 64 + ti * 16 + lm];
  }

  f32x4 acc[4][4];
#pragma unroll
  for (int i = 0; i < 4; ++i)
#pragma unroll
    for (int j = 0; j < 4; ++j) acc[i][j] = (f32x4)0.0f;

  for (int kt = 0; kt < 8; ++kt) {
    const int kc = kt * 32 + q8;
    bf16x8 bh[4], bl[4];
#pragma unroll
    for (int tj = 0; tj < 4; ++tj) {
      bh[tj] = ld16(P2H + (size_t)(tj * 16 + lm) * 256 + kc);
      bl[tj] = ld16(P2L + (size_t)(tj * 16 + lm) * 256 + kc);
    }
    float w08[8], w18[8], bb8[8];
#pragma unroll
    for (int j = 0; j < 8; ++j) { w08[j] = W0[kc + j]; w18[j] = W1[kc + j]; bb8[j] = Bb[kc + j]; }
#pragma unroll
    for (int ti = 0; ti < 4; ++ti) {
      float a8[8];
#pragma unroll
      for (int j = 0; j < 8; ++j)
        a8[j] = fmaxf(fmaf(sv0[ti], w08[j], fmaf(sv1[ti], w18[j], bb8[j])), 0.0f);
      bf16x8 ah, al;
      split8(a8, ah, al);
#pragma unroll
      for (int tj = 0; tj < 4; ++tj) acc[ti][tj] = mm3(ah, al, bh[tj], bl[tj], acc[ti][tj]);
    }
  }

  const int rq = (lane >> 4) * 4;
  const int rowbase = row0 + wave * 64;
#pragma unroll
  for (int ti = 0; ti < 4; ++ti)
#pragma unroll
    for (int tj = 0; tj < 4; ++tj) {
      const int col = tj * 16 + lm;
      const float bv = bp2[col];
#pragma unroll
      for (int r = 0; r < 4; ++r)
        X[(size_t)(rowbase + ti * 16 + rq + r) * 64 + col] = acc[ti][tj][r] + bv;
    }
}

// ---------------------------------------------------------------------------
// prez: G1t[dir][b][c:128][m:1024] (bf16 hi/lo) = transpose([x|h] @ [Wz|Wr])
// ---------------------------------------------------------------------------
__global__ __launch_bounds__(256) void prez_mfma(
    const float* __restrict__ x0p, const float* __restrict__ x1p,
    const float* __restrict__ h0p, const float* __restrict__ h1p,
    const ushort_t* __restrict__ WH, const ushort_t* __restrict__ WL,
    int l,
    ushort_t* __restrict__ G1tH, ushort_t* __restrict__ G1tL)
{
  __shared__ float T[128][132];
  const int tid = threadIdx.x;
  const int row0 = blockIdx.x * 128;
  const int dir  = blockIdx.z;
  const int b    = row0 >> 10;
  const int nloc = row0 & 1023;
  const float* __restrict__ xs = dir ? x1p : x0p;
  const float* __restrict__ hs = dir ? h1p : h0p;
  const ushort_t* BH = WH + WOFF_PZ + (size_t)(dir * 2 + l) * 16384;
  const ushort_t* BL = WL + WOFF_PZ + (size_t)(dir * 2 + l) * 16384;

  const int lane = tid & 63, wave = tid >> 6;
  const int wr = (wave >> 1) * 64, wc = (wave & 1) * 64;
  const int lm = lane & 15, q8 = (lane >> 4) * 8;

  f32x4 acc[4][4];
#pragma unroll
  for (int i = 0; i < 4; ++i)
#pragma unroll
    for (int j = 0; j < 4; ++j) acc[i][j] = (f32x4)0.0f;

#pragma unroll
  for (int kt = 0; kt < 4; ++kt) {
    const int k0 = kt * 32 + q8;
    bf16x8 bh[4], bl[4];
#pragma unroll
    for (int tj = 0; tj < 4; ++tj) {
      const size_t off = (size_t)(wc + tj * 16 + lm) * 128 + k0;
      bh[tj] = ld16(BH + off);
      bl[tj] = ld16(BL + off);
    }
#pragma unroll
    for (int ti = 0; ti < 4; ++ti) {
      const int row = row0 + wr + ti * 16 + lm;
      const float* src = (k0 < 64) ? (xs + (size_t)row * 64 + k0)
                                   : (hs + (size_t)row * 64 + (k0 - 64));
      float a8[8];
      ld8f(src, a8);
      bf16x8 ah, al;
      split8(a8, ah, al);
#pragma unroll
      for (int tj = 0; tj < 4; ++tj) acc[ti][tj] = mm3(ah, al, bh[tj], bl[tj], acc[ti][tj]);
    }
  }

  const int rq = (lane >> 4) * 4;
#pragma unroll
  for (int ti = 0; ti < 4; ++ti)
#pragma unroll
    for (int tj = 0; tj < 4; ++tj)
#pragma unroll
      for (int r = 0; r < 4; ++r)
        T[wc + tj * 16 + lm][wr + ti * 16 + rq + r] = acc[ti][tj][r];
  __syncthreads();

  {
    const int c = tid >> 1, mc = (tid & 1) * 64;
    const size_t base = ((size_t)(dir * 16 + b) * 128 + c) * 1024 + nloc + mc;
#pragma unroll
    for (int q = 0; q < 4; ++q) {
      alignas(16) ushort_t hsv[16], lsv[16];
#pragma unroll
      for (int k = 0; k < 16; ++k) {
        float v = T[c][mc + q * 16 + k];
        ushort_t h = f2bf_rne(v);
        hsv[k] = h;
        lsv[k] = f2bf_rne(v - bf2f(h));
      }
      *reinterpret_cast<uint4*>(G1tH + base + q * 16)     = *reinterpret_cast<uint4*>(&hsv[0]);
      *reinterpret_cast<uint4*>(G1tH + base + q * 16 + 8) = *reinterpret_cast<uint4*>(&hsv[8]);
      *reinterpret_cast<uint4*>(G1tL + base + q * 16)     = *reinterpret_cast<uint4*>(&lsv[0]);
      *reinterpret_cast<uint4*>(G1tL + base + q * 16 + 8) = *reinterpret_cast<uint4*>(&lsv[8]);
    }
  }
}

// ---------------------------------------------------------------------------
// prec: G2t[b][dir*64+c][m:1024] (bf16 hi/lo) = transpose([x|r*h] @ Wc)
// ---------------------------------------------------------------------------
__global__ __launch_bounds__(128) void prec_mfma(
    const float* __restrict__ x0p, const float* __restrict__ x1p,
    const float* __restrict__ rhbuf,
    const ushort_t* __restrict__ WH, const ushort_t* __restrict__ WL,
    int l,
    ushort_t* __restrict__ G2tH, ushort_t* __restrict__ G2tL)
{
  __shared__ float T[64][132];
  const int tid = threadIdx.x;
  const int row0 = blockIdx.x * 128;
  const int dir  = blockIdx.z;
  const int b    = row0 >> 10;
  const int nloc = row0 & 1023;
  const float* __restrict__ xs = dir ? x1p : x0p;
  const float* __restrict__ rs = rhbuf + (size_t)dir * ((size_t)ROWS * 64);
  const ushort_t* BH = WH + WOFF_PC + (size_t)(dir * 2 + l) * 8192;
  const ushort_t* BL = WL + WOFF_PC + (size_t)(dir * 2 + l) * 8192;

  const int lane = tid & 63, wave = tid >> 6;   // wave 0..1
  const int wr = wave * 64;
  const int lm = lane & 15, q8 = (lane >> 4) * 8;

  f32x4 acc[4][4];
#pragma unroll
  for (int i = 0; i < 4; ++i)
#pragma unroll
    for (int j = 0; j < 4; ++j) acc[i][j] = (f32x4)0.0f;

#pragma unroll
  for (int kt = 0; kt < 4; ++kt) {
    const int k0 = kt * 32 + q8;
    bf16x8 bh[4], bl[4];
#pragma unroll
    for (int tj = 0; tj < 4; ++tj) {
      const size_t off = (size_t)(tj * 16 + lm) * 128 + k0;
      bh[tj] = ld16(BH + off);
      bl[tj] = ld16(BL + off);
    }
#pragma unroll
    for (int ti = 0; ti < 4; ++ti) {
      const int row = row0 + wr + ti * 16 + lm;
      const float* src = (k0 < 64) ? (xs + (size_t)row * 64 + k0)
                                   : (rs + (size_t)row * 64 + (k0 - 64));
      float a8[8];
      ld8f(src, a8);
      bf16x8 ah, al;
      split8(a8, ah, al);
#pragma unroll
      for (int tj = 0; tj < 4; ++tj) acc[ti][tj] = mm3(ah, al, bh[tj], bl[tj], acc[ti][tj]);
    }
  }

  const int rq = (lane >> 4) * 4;
#pragma unroll
  for (int ti = 0; ti < 4; ++ti)
#pragma unroll
    for (int tj = 0; tj < 4; ++tj)
#pragma unroll
      for (int r = 0; r < 4; ++r)
        T[tj * 16 + lm][wr + ti * 16 + rq + r] = acc[ti][tj][r];
  __syncthreads();

  {
    const int c = tid >> 1, mc = (tid & 1) * 64;
    const size_t base = ((size_t)b * 128 + (size_t)dir * 64 + c) * 1024 + nloc + mc;
#pragma unroll
    for (int q = 0; q < 4; ++q) {
      alignas(16) ushort_t hsv[16], lsv[16];
#pragma unroll
      for (int k = 0; k < 16; ++k) {
        float v = T[c][mc + q * 16 + k];
        ushort_t h = f2bf_rne(v);
        hsv[k] = h;
        lsv[k] = f2bf_rne(v - bf2f(h));
      }
      *reinterpret_cast<uint4*>(G2tH + base + q * 16)     = *reinterpret_cast<uint4*>(&hsv[0]);
      *reinterpret_cast<uint4*>(G2tH + base + q * 16 + 8) = *reinterpret_cast<uint4*>(&hsv[8]);
      *reinterpret_cast<uint4*>(G2tL + base + q * 16)     = *reinterpret_cast<uint4*>(&lsv[0]);
      *reinterpret_cast<uint4*>(G2tL + base + q * 16 + 8) = *reinterpret_cast<uint4*>(&lsv[8]);
    }
  }
}

// ---------------------------------------------------------------------------
// conv_mfma: direct-from-global MFMA, NO LDS, NO barriers.
// Block = 128(n) x 64(c) tile; 4 waves in 2x2; acc 4x2; K-loop reg dbuf.
// grid.x: (x&7)=n0 tile, (x>>3)=sel. EPI=0: sel=gate half (0:z 1:r), dir=blockIdx.z.
// EPI=1: sel=dir (cols dir*64..).
// ---------------------------------------------------------------------------
template<int EPI>
__global__ __launch_bounds__(256) void conv_mfma(
    const ushort_t* __restrict__ adjHi, const ushort_t* __restrict__ adjLo,
    const ushort_t* __restrict__ BtH,  const ushort_t* __restrict__ BtL,
    const float* __restrict__ c0F, const float* __restrict__ c0R,
    const float* __restrict__ c1F, const float* __restrict__ c1R,
    float* __restrict__ zbuf, float* __restrict__ rhb,
    float* __restrict__ h0, float* __restrict__ h1)
{
  const int tid = threadIdx.x;
  const int n0  = (blockIdx.x & 7) * 128;
  const int sel = blockIdx.x >> 3;
  const int b   = blockIdx.y;
  const int dir = (EPI == 0) ? blockIdx.z : sel;

  const size_t boff = (EPI == 0)
      ? ((size_t)(dir * 16 + b) * 128 + sel * 64) * 1024
      : ((size_t)b * 128 + (size_t)sel * 64) * 1024;

  const int lane = tid & 63, wave = tid >> 6;
  const int wr = (wave >> 1) * 64, wc = (wave & 1) * 32;
  const int lm = lane & 15, q8 = (lane >> 4) * 8;

  size_t rowA[4], rowB[2];
#pragma unroll
  for (int ti = 0; ti < 4; ++ti)
    rowA[ti] = (size_t)(n0 + wr + ti * 16 + lm) * 1024 + q8;
#pragma unroll
  for (int tj = 0; tj < 2; ++tj)
    rowB[tj] = boff + (size_t)(wc + tj * 16 + lm) * 1024 + q8;

  f32x4 acc[4][2];
#pragma unroll
  for (int i = 0; i < 4; ++i)
#pragma unroll
    for (int j = 0; j < 2; ++j) acc[i][j] = (f32x4)0.0f;

  bf16x8 A0[4][2], B0[2][2], A1[4][2], B1[2][2];

#define CLOAD(Adst, Bdst, kt)                                    \
  {                                                              \
    const int _ko = (kt) * 32;                                   \
    _Pragma("unroll")                                            \
    for (int ti = 0; ti < 4; ++ti) {                             \
      Adst[ti][0] = ld16(adjHi + rowA[ti] + _ko);                \
      Adst[ti][1] = ld16(adjLo + rowA[ti] + _ko);                \
    }                                                            \
    _Pragma("unroll")                                            \
    for (int tj = 0; tj < 2; ++tj) {                             \
      Bdst[tj][0] = ld16(BtH + rowB[tj] + _ko);                  \
      Bdst[tj][1] = ld16(BtL + rowB[tj] + _ko);                  \
    }                                                            \
  }

#define CCOMP(Asrc, Bsrc)                                        \
  {                                                              \
    _Pragma("unroll")                                            \
    for (int ti = 0; ti < 4; ++ti)                               \
      _Pragma("unroll")                                          \
      for (int tj = 0; tj < 2; ++tj)                             \
        acc[ti][tj] = mm3(Asrc[ti][0], Asrc[ti][1],              \
                          Bsrc[tj][0], Bsrc[tj][1], acc[ti][tj]);\
  }

  CLOAD(A0, B0, 0)
  for (int kt = 0; kt < 32; kt += 2) {
    CLOAD(A1, B1, kt + 1)
    CCOMP(A0, B0)
    if (kt + 2 < 32) CLOAD(A0, B0, kt + 2)
    CCOMP(A1, B1)
  }
#undef CLOAD
#undef CCOMP

  const int rq = (lane >> 4) * 4;
  const size_t rowbase = (size_t)b * 1024 + n0 + wr;

  if (EPI == 0) {
    float* zb = zbuf + (size_t)dir * ((size_t)ROWS * 64);
    float* rb = rhb  + (size_t)dir * ((size_t)ROWS * 64);
    const float* hb = dir ? h1 : h0;
    if (sel == 0) {                      // z gate
      const float* bz = dir ? c0R : c0F;
#pragma unroll
      for (int ti = 0; ti < 4; ++ti)
#pragma unroll
        for (int tj = 0; tj < 2; ++tj) {
          const int c = wc + tj * 16 + lm;
          const float bv = bz[c];
#pragma unroll
          for (int r = 0; r < 4; ++r) {
            const size_t row = rowbase + ti * 16 + rq + r;
            zb[row * 64 + c] = sigmoidf_(acc[ti][tj][r] + bv);
          }
        }
    } else {                             // r gate -> rh
      const float* br = dir ? c1R : c1F;
#pragma unroll
      for (int ti = 0; ti < 4; ++ti)
#pragma unroll
        for (int tj = 0; tj < 2; ++tj) {
          const int c = wc + tj * 16 + lm;
          const float bv = br[c];
#pragma unroll
          for (int r = 0; r < 4; ++r) {
            const size_t row = rowbase + ti * 16 + rq + r;
            const float rr = sigmoidf_(acc[ti][tj][r] + bv);
            rb[row * 64 + c] = rr * hb[row * 64 + c];
          }
        }
    }
  } else {
    const float* bc = sel ? c0R : c0F;
    const float* zb = zbuf + (size_t)sel * ((size_t)ROWS * 64);
    float* hb = sel ? h1 : h0;
#pragma unroll
    for (int ti = 0; ti < 4; ++ti)
#pragma unroll
      for (int tj = 0; tj < 2; ++tj) {
        const int c = wc + tj * 16 + lm;
        const float bv = bc[c];
#pragma unroll
        for (int r = 0; r < 4; ++r) {
          const size_t row = rowbase + ti * 16 + rq + r;
          const size_t idx = row * 64 + c;
          const float cc = tanhf(acc[ti][tj][r] + bv);
          const float z = zb[idx];
          const float hv = hb[idx];
          hb[idx] = z * hv + (1.0f - z) * cc;
        }
      }
  }
}

// ---------------------------------------------------------------------------
// dec1: D1[row][256] = relu(concat(hid_f,hid_r)[row] @ Wd1 + bd1)
// ---------------------------------------------------------------------------
__global__ __launch_bounds__(256) void dec1_mfma(
    const float* __restrict__ Hws,
    const ushort_t* __restrict__ WH, const ushort_t* __restrict__ WL,
    const float* __restrict__ bd1,
    float* __restrict__ D1)
{
  const int tid = threadIdx.x;
  const int row0 = blockIdx.x * 128;
  const int cb   = blockIdx.y * 128;
  const int l  = row0 >> 14;
  const int ri0 = row0 & 16383;
  const float* Hf = Hws + (size_t)l * HSZ;
  const float* Hr = Hws + (size_t)(2 + l) * HSZ;
  const ushort_t* BH = WH + WOFF_D1;
  const ushort_t* BL = WL + WOFF_D1;

  const int lane = tid & 63, wave = tid >> 6;
  const int wr = (wave >> 1) * 64, wc = (wave & 1) * 64;
  const int lm = lane & 15, q8 = (lane >> 4) * 8;

  f32x4 acc[4][4];
#pragma unroll
  for (int i = 0; i < 4; ++i)
#pragma unroll
    for (int j = 0; j < 4; ++j) acc[i][j] = (f32x4)0.0f;

#pragma unroll
  for (int kt = 0; kt < 4; ++kt) {
    const int k0 = kt * 32 + q8;
    bf16x8 bh[4], bl[4];
#pragma unroll
    for (int tj = 0; tj < 4; ++tj) {
      const size_t off = (size_t)(cb + wc + tj * 16 + lm) * 128 + k0;
      bh[tj] = ld16(BH + off);
      bl[tj] = ld16(BL + off);
    }
#pragma unroll
    for (int ti = 0; ti < 4; ++ti) {
      const int ri = ri0 + wr + ti * 16 + lm;
      const float* src = (k0 < 64) ? (Hf + (size_t)ri * 64 + k0)
                                   : (Hr + (size_t)ri * 64 + (k0 - 64));
      float a8[8];
      ld8f(src, a8);
      bf16x8 ah, al;
      split8(a8, ah, al);
#pragma unroll
      for (int tj = 0; tj < 4; ++tj) acc[ti][tj] = mm3(ah, al, bh[tj], bl[tj], acc[ti][tj]);
    }
  }

  const int rq = (lane >> 4) * 4;
#pragma unroll
  for (int ti = 0; ti < 4; ++ti)
#pragma unroll
    for (int tj = 0; tj < 4; ++tj) {
      const int col = cb + wc + tj * 16 + lm;
      const float bv = bd1[col];
#pragma unroll
      for (int r = 0; r < 4; ++r) {
        const size_t row = row0 + wr + ti * 16 + rq + r;
        D1[row * 256 + col] = fmaxf(acc[ti][tj][r] + bv, 0.0f);
      }
    }
}

// ---------------------------------------------------------------------------
// dec2: out[row][64] = D1[row] @ Wd2 + bd2.  Block 256 rows. Grid 128.
// ---------------------------------------------------------------------------
__global__ __launch_bounds__(256) void dec2_mfma(
    const float* __restrict__ D1,
    const ushort_t* __restrict__ WH, const ushort_t* __restrict__ WL,
    const float* __restrict__ bd2,
    float* __restrict__ out)
{
  const int tid = threadIdx.x;
  const int row0 = blockIdx.x * 256;
  const ushort_t* BH = WH + WOFF_D2;
  const ushort_t* BL = WL + WOFF_D2;

  const int lane = tid & 63, wave = tid >> 6;
  const int wr = wave * 64;
  const int lm = lane & 15, q8 = (lane >> 4) * 8;

  f32x4 acc[4][4];
#pragma unroll
  for (int i = 0; i < 4; ++i)
#pragma unroll
    for (int j = 0; j < 4; ++j) acc[i][j] = (f32x4)0.0f;

#pragma unroll
  for (int kt = 0; kt < 8; ++kt) {
    const int k0 = kt * 32 + q8;
    bf16x8 bh[4], bl[4];
#pragma unroll
    for (int tj = 0; tj < 4; ++tj) {
      const size_t off = (size_t)(tj * 16 + lm) * 256 + k0;
      bh[tj] = ld16(BH + off);
      bl[tj] = ld16(BL + off);
    }
#pragma unroll
    for (int ti = 0; ti < 4; ++ti) {
      const size_t row = row0 + wr + ti * 16 + lm;
      float a8[8];
      ld8f(D1 + row * 256 + k0, a8);
      bf16x8 ah, al;
      split8(a8, ah, al);
#pragma unroll
      for (int tj = 0; tj < 4; ++tj) acc[ti][tj] = mm3(ah, al, bh[tj], bl[tj], acc[ti][tj]);
    }
  }

  const int rq = (lane >> 4) * 4;
#pragma unroll
  for (int ti = 0; ti < 4; ++ti)
#pragma unroll
    for (int tj = 0; tj < 4; ++tj) {
      const int col = tj * 16 + lm;
      const float bv = bd2[col];
#pragma unroll
      for (int r = 0; r < 4; ++r) {
        const size_t row = row0 + wr + ti * 16 + rq + r;
        out[row * 64 + col] = acc[ti][tj][r] + bv;
      }
    }
}

// ---------------------------------------------------------------------------
// Host driver
// ---------------------------------------------------------------------------
extern "C" void kernel_launch(void* const* d_in, const int* in_sizes, int n_in,
                              void* d_out, int out_size, void* d_ws, size_t ws_size,
                              hipStream_t stream)
{
  (void)in_sizes; (void)n_in; (void)out_size; (void)ws_size;
  const float* inputs = (const float*)d_in[0];
  const float* mask   = (const float*)d_in[1];
  const float* adj    = (const float*)d_in[2];
  const float* Wp1    = (const float*)d_in[3];
  const float* bp1    = (const float*)d_in[4];
  const float* Wp2    = (const float*)d_in[5];
  const float* bp2    = (const float*)d_in[6];
  const float* Wz_f   = (const float*)d_in[7];
  const float* Wr_f   = (const float*)d_in[8];
  const float* Wc_f   = (const float*)d_in[9];
  const float* bz_f   = (const float*)d_in[10];
  const float* br_f   = (const float*)d_in[11];
  const float* bc_f   = (const float*)d_in[12];
  const float* Wz_r   = (const float*)d_in[13];
  const float* Wr_r   = (const float*)d_in[14];
  const float* Wc_r   = (const float*)d_in[15];
  const float* bz_r   = (const float*)d_in[16];
  const float* br_r   = (const float*)d_in[17];
  const float* bc_r   = (const float*)d_in[18];
  const float* Wd1    = (const float*)d_in[19];
  const float* bd1    = (const float*)d_in[20];
  const float* Wd2    = (const float*)d_in[21];
  const float* bd2    = (const float*)d_in[22];

  float* ws = (float*)d_ws;
  float* S0 = ws;                                   // TOT
  float* X  = S0 + TOT;                             // TOT*64
  float* H  = X + (size_t)TOT * 64;                 // 4*HSZ [dir*2+l]
  float* Z  = H + 4 * HSZ;                          // 2*HSZ
  float* RH = Z + 2 * HSZ;                          // 2*HSZ
  ushort_t* ADJH = (ushort_t*)(RH + 2 * HSZ);       // 1M ushorts
  ushort_t* ADJL = ADJH + (size_t)1024 * 1024;
  ushort_t* WH   = ADJL + (size_t)1024 * 1024;      // WTOT
  ushort_t* WL   = WH + WTOT;
  float* U = (float*)(WL + WTOT);                   // union region
  ushort_t* G1TH = (ushort_t*)U;
  ushort_t* G1TL = G1TH + (size_t)2 * 16 * 128 * 1024;
  ushort_t* G2TH = G1TL + (size_t)2 * 16 * 128 * 1024;
  ushort_t* G2TL = G2TH + (size_t)16 * 128 * 1024;
  float* D1 = U;                                    // aliases G after loop

  hipMemsetAsync(H, 0, 4 * HSZ * sizeof(float), stream);

  seq_kernel<<<dim3((HALF + 255) / 256), 256, 0, stream>>>(inputs, S0);
  wprep_kernel<<<dim3((WTOT + 255) / 256), 256, 0, stream>>>(
      Wz_f, Wr_f, Wc_f, Wz_r, Wr_r, Wc_r, Wp2, Wd1, Wd2, WH, WL);
  adjsplit_kernel<<<dim3(4096), 256, 0, stream>>>(adj, ADJH, ADJL);
  proj_mfma<<<dim3(TOT / 256), 256, 0, stream>>>(S0, mask, Wp1, bp1, bp2, WH, WL, X);

  for (int t = 0; t < Tn; ++t) {
    for (int l = 0; l < Ln; ++l) {
      const float* x0 = (l == 0) ? (X + (size_t)t * HSZ) : H;
      const float* x1 = (l == 0) ? (X + (size_t)(Tn - 1 - t) * HSZ) : (H + 2 * HSZ);
      float* h0 = H + (size_t)l * HSZ;
      float* h1 = H + (size_t)(2 + l) * HSZ;

      prez_mfma<<<dim3(128, 1, 2), 256, 0, stream>>>(
          x0, x1, h0, h1, WH, WL, l, G1TH, G1TL);
      conv_mfma<0><<<dim3(16, 16, 2), 256, 0, stream>>>(
          ADJH, ADJL, G1TH, G1TL,
          bz_f + l * 64, bz_r + l * 64, br_f + l * 64, br_r + l * 64,
          Z, RH, h0, h1);
      prec_mfma<<<dim3(128, 1, 2), 128, 0, stream>>>(
          x0, x1, RH, WH, WL, l, G2TH, G2TL);
      conv_mfma<1><<<dim3(16, 16, 1), 256, 0, stream>>>(
          ADJH, ADJL, G2TH, G2TL,
          bc_f + l * 64, bc_r + l * 64, bc_f + l * 64, bc_r + l * 64,
          Z, RH, h0, h1);
    }
  }

  dec1_mfma<<<dim3(256, 2), 256, 0, stream>>>(H, WH, WL, bd1, D1);
  dec2_mfma<<<dim3(128), 256, 0, stream>>>(D1, WH, WL, bd2, (float*)d_out);
}

// Round 6
// 3154.393 us; speedup vs baseline: 1.3920x; 1.3920x over previous
//
#include <hip/hip_runtime.h>
#include <cstdint>
#include <cstddef>

constexpr int Tn = 12, Bn = 16, Nn = 1024, Hn = 64, Ln = 2;
constexpr int ROWS = Bn * Nn;                 // 16384
constexpr int TOT  = Tn * Bn * Nn;            // 196608
constexpr int HALF = TOT / 2;
constexpr size_t HSZ = (size_t)Bn * Nn * Hn;  // 1048576 floats

#define DEVFN __device__ __forceinline__

typedef __attribute__((ext_vector_type(4))) float f32x4;
typedef __attribute__((ext_vector_type(8))) __bf16 bf16x8;
typedef unsigned short ushort_t;

// weight-plane offsets (in elements) inside WH/WL
constexpr size_t WOFF_PZ = 0;        // [d][l][n:128][k:128]  prez B
constexpr size_t WOFF_PC = 65536;    // [d][l][n:64][k:128]   prec B
constexpr size_t WOFF_P2 = 98304;    // [n:64][k:256]         proj B (Wp2)
constexpr size_t WOFF_D1 = 114688;   // [n:256][k:128]        dec1 B (Wd1)
constexpr size_t WOFF_D2 = 147456;   // [n:64][k:256]         dec2 B (Wd2)
constexpr size_t WTOT    = 163840;

// ---------------------------------------------------------------------------
// bf16 split helpers (RNE)
// ---------------------------------------------------------------------------
DEVFN ushort_t f2bf_rne(float f) {
  uint32_t u = __float_as_uint(f);
  uint32_t r = u + 0x7FFFu + ((u >> 16) & 1u);
  return (ushort_t)(r >> 16);
}
DEVFN float bf2f(ushort_t h) { return __uint_as_float(((uint32_t)h) << 16); }

DEVFN void split8(const float* f, bf16x8& h8, bf16x8& l8) {
  alignas(16) ushort_t hs[8], ls[8];
#pragma unroll
  for (int j = 0; j < 8; ++j) {
    ushort_t h = f2bf_rne(f[j]);
    hs[j] = h;
    ls[j] = f2bf_rne(f[j] - bf2f(h));
  }
  h8 = *reinterpret_cast<bf16x8*>(hs);
  l8 = *reinterpret_cast<bf16x8*>(ls);
}

DEVFN f32x4 mm3(bf16x8 ah, bf16x8 al, bf16x8 bh, bf16x8 bl, f32x4 c) {
  c = __builtin_amdgcn_mfma_f32_16x16x32_bf16(ah, bh, c, 0, 0, 0);
  c = __builtin_amdgcn_mfma_f32_16x16x32_bf16(ah, bl, c, 0, 0, 0);
  c = __builtin_amdgcn_mfma_f32_16x16x32_bf16(al, bh, c, 0, 0, 0);
  return c;
}

DEVFN bf16x8 ld16(const ushort_t* p) { return *reinterpret_cast<const bf16x8*>(p); }

DEVFN void ld8f(const float* p, float* out) {
  float4 v0 = *reinterpret_cast<const float4*>(p);
  float4 v1 = *reinterpret_cast<const float4*>(p + 4);
  out[0] = v0.x; out[1] = v0.y; out[2] = v0.z; out[3] = v0.w;
  out[4] = v1.x; out[5] = v1.y; out[6] = v1.z; out[7] = v1.w;
}

// async global->LDS, 16B per lane. LDS dest = base + lane*16 (wave-uniform base).
DEVFN void async16(const ushort_t* g, ushort_t* l) {
  __builtin_amdgcn_global_load_lds(
      (const __attribute__((address_space(1))) uint32_t*)g,
      (__attribute__((address_space(3))) uint32_t*)l, 16, 0, 0);
}

// LDS fragment layout: [group=row>>4][q=0..3][r=row&15][8 elems]
// frag offset for 16-row-aligned base rb and lane:
DEVFN int foff(int rb, int lane) {
  return ((rb) >> 4) * 512 + (lane >> 4) * 128 + (lane & 15) * 8;
}

// ---------------------------------------------------------------------------
// threefry2x32 (key 0,42) + XLA-exact normal
// ---------------------------------------------------------------------------
DEVFN uint32_t rotl32(uint32_t v, int d) { return (v << d) | (v >> (32 - d)); }

DEVFN void threefry_0_42(uint32_t& x0, uint32_t& x1) {
  const uint32_t k0 = 0u, k1 = 42u, k2 = k0 ^ k1 ^ 0x1BD11BDAu;
  x0 += k0; x1 += k1;
#define TFR(r) { x0 += x1; x1 = rotl32(x1, r); x1 ^= x0; }
  TFR(13) TFR(15) TFR(26) TFR(6)
  x0 += k1; x1 += k2 + 1u;
  TFR(17) TFR(29) TFR(16) TFR(24)
  x0 += k2; x1 += k0 + 2u;
  TFR(13) TFR(15) TFR(26) TFR(6)
  x0 += k0; x1 += k1 + 3u;
  TFR(17) TFR(29) TFR(16) TFR(24)
  x0 += k1; x1 += k2 + 4u;
  TFR(13) TFR(15) TFR(26) TFR(6)
  x0 += k2; x1 += k0 + 5u;
#undef TFR
}

DEVFN float erfinv32(float x) {
  float w = -log1pf(-x * x);
  float p;
  if (w < 5.0f) {
    w = w - 2.5f;
    p = 2.81022636e-08f;
    p = fmaf(p, w, 3.43273939e-07f);
    p = fmaf(p, w, -3.5233877e-06f);
    p = fmaf(p, w, -4.39150654e-06f);
    p = fmaf(p, w, 0.00021858087f);
    p = fmaf(p, w, -0.00125372503f);
    p = fmaf(p, w, -0.00417768164f);
    p = fmaf(p, w, 0.246640727f);
    p = fmaf(p, w, 1.50140941f);
  } else {
    w = sqrtf(w) - 3.0f;
    p = -0.000200214257f;
    p = fmaf(p, w, 0.000100950558f);
    p = fmaf(p, w, 0.00134934322f);
    p = fmaf(p, w, -0.00367342844f);
    p = fmaf(p, w, 0.00573950773f);
    p = fmaf(p, w, -0.0076224613f);
    p = fmaf(p, w, 0.00943887047f);
    p = fmaf(p, w, 1.00167406f);
    p = fmaf(p, w, 2.83297682f);
  }
  return p * x;
}

DEVFN float bits_to_normal(uint32_t bits) {
  float f = __uint_as_float((bits >> 9) | 0x3f800000u) - 1.0f;
  const float lo = -0.99999994f;
  float u = fmaf(f, 2.0f, lo);
  u = fmaxf(lo, u);
  return 1.41421356237f * erfinv32(u);
}

__global__ __launch_bounds__(256) void seq_kernel(const float* __restrict__ inputs,
                                                  float* __restrict__ s0) {
  int i = blockIdx.x * 256 + threadIdx.x;
  if (i >= HALF) return;
  uint32_t x0 = (uint32_t)i, x1 = (uint32_t)(i + HALF);
  threefry_0_42(x0, x1);
  s0[i]        = inputs[i]        + 0.01f * bits_to_normal(x0);
  s0[i + HALF] = inputs[i + HALF] + 0.01f * bits_to_normal(x1);
}

DEVFN float sigmoidf_(float x) { return 1.0f / (1.0f + expf(-x)); }

// ---------------------------------------------------------------------------
// adj -> bf16 hi/lo planes
// ---------------------------------------------------------------------------
__global__ __launch_bounds__(256) void adjsplit_kernel(const float* __restrict__ adj,
                                                       ushort_t* __restrict__ hi,
                                                       ushort_t* __restrict__ lo) {
  int i = blockIdx.x * 256 + threadIdx.x;
  float v = adj[i];
  ushort_t h = f2bf_rne(v);
  hi[i] = h;
  lo[i] = f2bf_rne(v - bf2f(h));
}

// ---------------------------------------------------------------------------
// wprep: split + transpose all GEMM B-weights into [n][k] bf16 hi/lo planes
// ---------------------------------------------------------------------------
__global__ __launch_bounds__(256) void wprep_kernel(
    const float* __restrict__ WzF, const float* __restrict__ WrF, const float* __restrict__ WcF,
    const float* __restrict__ WzR, const float* __restrict__ WrR, const float* __restrict__ WcR,
    const float* __restrict__ Wp2, const float* __restrict__ Wd1, const float* __restrict__ Wd2,
    ushort_t* __restrict__ WH, ushort_t* __restrict__ WL)
{
  size_t i = (size_t)blockIdx.x * 256 + threadIdx.x;
  if (i >= WTOT) return;
  float v;
  if (i < WOFF_PC) {                          // PZ [d][l][n:128][k:128]
    int d = (i >> 15) & 1, l = (i >> 14) & 1, n = (i >> 7) & 127, k = i & 127;
    const float* W = (n < 64) ? (d ? WzR : WzF) : (d ? WrR : WrF);
    v = W[l * 8192 + k * 64 + (n & 63)];
  } else if (i < WOFF_P2) {                   // PC [d][l][n:64][k:128]
    size_t j = i - WOFF_PC;
    int d = (j >> 14) & 1, l = (j >> 13) & 1, n = (j >> 7) & 63, k = j & 127;
    const float* W = d ? WcR : WcF;
    v = W[l * 8192 + k * 64 + n];
  } else if (i < WOFF_D1) {                   // P2 [n:64][k:256]
    size_t j = i - WOFF_P2;
    int n = j >> 8, k = j & 255;
    v = Wp2[k * 64 + n];
  } else if (i < WOFF_D2) {                   // D1 [n:256][k:128]
    size_t j = i - WOFF_D1;
    int n = j >> 7, k = j & 127;
    v = Wd1[k * 256 + n];
  } else {                                    // D2 [n:64][k:256]
    size_t j = i - WOFF_D2;
    int n = j >> 8, k = j & 255;
    v = Wd2[k * 64 + n];
  }
  ushort_t h = f2bf_rne(v);
  WH[i] = h;
  WL[i] = f2bf_rne(v - bf2f(h));
}

// ---------------------------------------------------------------------------
// proj: X[m][64] = relu(s0*W0+s1*W1+bp1) @ Wp2 + bp2   (M=196608,N=64,K=256)
// ---------------------------------------------------------------------------
__global__ __launch_bounds__(256) void proj_mfma(
    const float* __restrict__ s0g, const float* __restrict__ s1g,
    const float* __restrict__ Wp1, const float* __restrict__ bp1,
    const float* __restrict__ bp2,
    const ushort_t* __restrict__ WH, const ushort_t* __restrict__ WL,
    float* __restrict__ X)
{
  __shared__ float W0[256], W1[256], Bb[256], SS0[256], SS1[256];
  const int tid = threadIdx.x;
  const int row0 = blockIdx.x * 256;
  W0[tid] = Wp1[tid];
  W1[tid] = Wp1[256 + tid];
  Bb[tid] = bp1[tid];
  SS0[tid] = s0g[row0 + tid];
  SS1[tid] = s1g[row0 + tid];
  __syncthreads();

  const int lane = tid & 63, wave = tid >> 6;
  const int lm = lane & 15, q8 = (lane >> 4) * 8;
  const ushort_t* P2H = WH + WOFF_P2;
  const ushort_t* P2L = WL + WOFF_P2;

  float sv0[4], sv1[4];
#pragma unroll
  for (int ti = 0; ti < 4; ++ti) {
    sv0[ti] = SS0[wave * 64 + ti * 16 + lm];
    sv1[ti] = SS1[wave * 64 + ti * 16 + lm];
  }

  f32x4 acc[4][4];
#pragma unroll
  for (int i = 0; i < 4; ++i)
#pragma unroll
    for (int j = 0; j < 4; ++j) acc[i][j] = (f32x4)0.0f;

  for (int kt = 0; kt < 8; ++kt) {
    const int kc = kt * 32 + q8;
    bf16x8 bh[4], bl[4];
#pragma unroll
    for (int tj = 0; tj < 4; ++tj) {
      bh[tj] = ld16(P2H + (size_t)(tj * 16 + lm) * 256 + kc);
      bl[tj] = ld16(P2L + (size_t)(tj * 16 + lm) * 256 + kc);
    }
    float w08[8], w18[8], bb8[8];
#pragma unroll
    for (int j = 0; j < 8; ++j) { w08[j] = W0[kc + j]; w18[j] = W1[kc + j]; bb8[j] = Bb[kc + j]; }
#pragma unroll
    for (int ti = 0; ti < 4; ++ti) {
      float a8[8];
#pragma unroll
      for (int j = 0; j < 8; ++j)
        a8[j] = fmaxf(fmaf(sv0[ti], w08[j], fmaf(sv1[ti], w18[j], bb8[j])), 0.0f);
      bf16x8 ah, al;
      split8(a8, ah, al);
#pragma unroll
      for (int tj = 0; tj < 4; ++tj) acc[ti][tj] = mm3(ah, al, bh[tj], bl[tj], acc[ti][tj]);
    }
  }

  const int rq = (lane >> 4) * 4;
  const int rowbase = row0 + wave * 64;
#pragma unroll
  for (int ti = 0; ti < 4; ++ti)
#pragma unroll
    for (int tj = 0; tj < 4; ++tj) {
      const int col = tj * 16 + lm;
      const float bv = bp2[col];
#pragma unroll
      for (int r = 0; r < 4; ++r)
        X[(size_t)(rowbase + ti * 16 + rq + r) * 64 + col] = acc[ti][tj][r] + bv;
    }
}

// ---------------------------------------------------------------------------
// prez: G1t[dir][b][c:128][m:1024] (bf16 hi/lo) = transpose([x|h] @ [Wz|Wr])
// ---------------------------------------------------------------------------
__global__ __launch_bounds__(256) void prez_mfma(
    const float* __restrict__ x0p, const float* __restrict__ x1p,
    const float* __restrict__ h0p, const float* __restrict__ h1p,
    const ushort_t* __restrict__ WH, const ushort_t* __restrict__ WL,
    int l,
    ushort_t* __restrict__ G1tH, ushort_t* __restrict__ G1tL)
{
  __shared__ float T[128][132];
  const int tid = threadIdx.x;
  const int row0 = blockIdx.x * 128;
  const int dir  = blockIdx.z;
  const int b    = row0 >> 10;
  const int nloc = row0 & 1023;
  const float* __restrict__ xs = dir ? x1p : x0p;
  const float* __restrict__ hs = dir ? h1p : h0p;
  const ushort_t* BH = WH + WOFF_PZ + (size_t)(dir * 2 + l) * 16384;
  const ushort_t* BL = WL + WOFF_PZ + (size_t)(dir * 2 + l) * 16384;

  const int lane = tid & 63, wave = tid >> 6;
  const int wr = (wave >> 1) * 64, wc = (wave & 1) * 64;
  const int lm = lane & 15, q8 = (lane >> 4) * 8;

  f32x4 acc[4][4];
#pragma unroll
  for (int i = 0; i < 4; ++i)
#pragma unroll
    for (int j = 0; j < 4; ++j) acc[i][j] = (f32x4)0.0f;

#pragma unroll
  for (int kt = 0; kt < 4; ++kt) {
    const int k0 = kt * 32 + q8;
    bf16x8 bh[4], bl[4];
#pragma unroll
    for (int tj = 0; tj < 4; ++tj) {
      const size_t off = (size_t)(wc + tj * 16 + lm) * 128 + k0;
      bh[tj] = ld16(BH + off);
      bl[tj] = ld16(BL + off);
    }
#pragma unroll
    for (int ti = 0; ti < 4; ++ti) {
      const int row = row0 + wr + ti * 16 + lm;
      const float* src = (k0 < 64) ? (xs + (size_t)row * 64 + k0)
                                   : (hs + (size_t)row * 64 + (k0 - 64));
      float a8[8];
      ld8f(src, a8);
      bf16x8 ah, al;
      split8(a8, ah, al);
#pragma unroll
      for (int tj = 0; tj < 4; ++tj) acc[ti][tj] = mm3(ah, al, bh[tj], bl[tj], acc[ti][tj]);
    }
  }

  const int rq = (lane >> 4) * 4;
#pragma unroll
  for (int ti = 0; ti < 4; ++ti)
#pragma unroll
    for (int tj = 0; tj < 4; ++tj)
#pragma unroll
      for (int r = 0; r < 4; ++r)
        T[wc + tj * 16 + lm][wr + ti * 16 + rq + r] = acc[ti][tj][r];
  __syncthreads();

  {
    const int c = tid >> 1, mc = (tid & 1) * 64;
    const size_t base = ((size_t)(dir * 16 + b) * 128 + c) * 1024 + nloc + mc;
#pragma unroll
    for (int q = 0; q < 4; ++q) {
      alignas(16) ushort_t hsv[16], lsv[16];
#pragma unroll
      for (int k = 0; k < 16; ++k) {
        float v = T[c][mc + q * 16 + k];
        ushort_t h = f2bf_rne(v);
        hsv[k] = h;
        lsv[k] = f2bf_rne(v - bf2f(h));
      }
      *reinterpret_cast<uint4*>(G1tH + base + q * 16)     = *reinterpret_cast<uint4*>(&hsv[0]);
      *reinterpret_cast<uint4*>(G1tH + base + q * 16 + 8) = *reinterpret_cast<uint4*>(&hsv[8]);
      *reinterpret_cast<uint4*>(G1tL + base + q * 16)     = *reinterpret_cast<uint4*>(&lsv[0]);
      *reinterpret_cast<uint4*>(G1tL + base + q * 16 + 8) = *reinterpret_cast<uint4*>(&lsv[8]);
    }
  }
}

// ---------------------------------------------------------------------------
// prec: G2t[b][dir*64+c][m:1024] (bf16 hi/lo) = transpose([x|r*h] @ Wc)
// ---------------------------------------------------------------------------
__global__ __launch_bounds__(128) void prec_mfma(
    const float* __restrict__ x0p, const float* __restrict__ x1p,
    const float* __restrict__ rhbuf,
    const ushort_t* __restrict__ WH, const ushort_t* __restrict__ WL,
    int l,
    ushort_t* __restrict__ G2tH, ushort_t* __restrict__ G2tL)
{
  __shared__ float T[64][132];
  const int tid = threadIdx.x;
  const int row0 = blockIdx.x * 128;
  const int dir  = blockIdx.z;
  const int b    = row0 >> 10;
  const int nloc = row0 & 1023;
  const float* __restrict__ xs = dir ? x1p : x0p;
  const float* __restrict__ rs = rhbuf + (size_t)dir * ((size_t)ROWS * 64);
  const ushort_t* BH = WH + WOFF_PC + (size_t)(dir * 2 + l) * 8192;
  const ushort_t* BL = WL + WOFF_PC + (size_t)(dir * 2 + l) * 8192;

  const int lane = tid & 63, wave = tid >> 6;   // wave 0..1
  const int wr = wave * 64;
  const int lm = lane & 15, q8 = (lane >> 4) * 8;

  f32x4 acc[4][4];
#pragma unroll
  for (int i = 0; i < 4; ++i)
#pragma unroll
    for (int j = 0; j < 4; ++j) acc[i][j] = (f32x4)0.0f;

#pragma unroll
  for (int kt = 0; kt < 4; ++kt) {
    const int k0 = kt * 32 + q8;
    bf16x8 bh[4], bl[4];
#pragma unroll
    for (int tj = 0; tj < 4; ++tj) {
      const size_t off = (size_t)(tj * 16 + lm) * 128 + k0;
      bh[tj] = ld16(BH + off);
      bl[tj] = ld16(BL + off);
    }
#pragma unroll
    for (int ti = 0; ti < 4; ++ti) {
      const int row = row0 + wr + ti * 16 + lm;
      const float* src = (k0 < 64) ? (xs + (size_t)row * 64 + k0)
                                   : (rs + (size_t)row * 64 + (k0 - 64));
      float a8[8];
      ld8f(src, a8);
      bf16x8 ah, al;
      split8(a8, ah, al);
#pragma unroll
      for (int tj = 0; tj < 4; ++tj) acc[ti][tj] = mm3(ah, al, bh[tj], bl[tj], acc[ti][tj]);
    }
  }

  const int rq = (lane >> 4) * 4;
#pragma unroll
  for (int ti = 0; ti < 4; ++ti)
#pragma unroll
    for (int tj = 0; tj < 4; ++tj)
#pragma unroll
      for (int r = 0; r < 4; ++r)
        T[tj * 16 + lm][wr + ti * 16 + rq + r] = acc[ti][tj][r];
  __syncthreads();

  {
    const int c = tid >> 1, mc = (tid & 1) * 64;
    const size_t base = ((size_t)b * 128 + (size_t)dir * 64 + c) * 1024 + nloc + mc;
#pragma unroll
    for (int q = 0; q < 4; ++q) {
      alignas(16) ushort_t hsv[16], lsv[16];
#pragma unroll
      for (int k = 0; k < 16; ++k) {
        float v = T[c][mc + q * 16 + k];
        ushort_t h = f2bf_rne(v);
        hsv[k] = h;
        lsv[k] = f2bf_rne(v - bf2f(h));
      }
      *reinterpret_cast<uint4*>(G2tH + base + q * 16)     = *reinterpret_cast<uint4*>(&hsv[0]);
      *reinterpret_cast<uint4*>(G2tH + base + q * 16 + 8) = *reinterpret_cast<uint4*>(&hsv[8]);
      *reinterpret_cast<uint4*>(G2tL + base + q * 16)     = *reinterpret_cast<uint4*>(&lsv[0]);
      *reinterpret_cast<uint4*>(G2tL + base + q * 16 + 8) = *reinterpret_cast<uint4*>(&lsv[8]);
    }
  }
}

// ---------------------------------------------------------------------------
// conv_mfma: LDS-staged via global_load_lds(16B), swizzled conflict-free layout.
// EPI=0: tile 128n x 64c, grid (8,16,4) z=dir*2+gsel (gsel: 0=z-gate, 1=r-gate)
// EPI=1: tile 128n x 32c, grid (8,16,4) z=dir*2+csel (csel: col half within dir)
// 256 thr, 4 waves. LDS layout per plane: [group=row>>4][q:4][r:16][8 elems].
// ---------------------------------------------------------------------------
template<int EPI>
__global__ __launch_bounds__(256) void conv_mfma(
    const ushort_t* __restrict__ adjHi, const ushort_t* __restrict__ adjLo,
    const ushort_t* __restrict__ BtH,  const ushort_t* __restrict__ BtL,
    const float* __restrict__ c0F, const float* __restrict__ c0R,
    const float* __restrict__ c1F, const float* __restrict__ c1R,
    float* __restrict__ zbuf, float* __restrict__ rhb,
    float* __restrict__ h0, float* __restrict__ h1)
{
  constexpr int TI = (EPI == 0) ? 4 : 2;     // 16-row acc tiles per wave
  constexpr int TJ = 2;                      // 16-col acc tiles per wave
  constexpr int BROWS = (EPI == 0) ? 64 : 32;

  __shared__ ushort_t AhS[4096], AlS[4096];
  __shared__ ushort_t BhS[BROWS * 32], BlS[BROWS * 32];

  const int tid = threadIdx.x;
  const int n0  = blockIdx.x * 128;
  const int b   = blockIdx.y;
  const int z   = blockIdx.z;
  const int dir = z >> 1, sel = z & 1;

  const size_t boff = (EPI == 0)
      ? ((size_t)(dir * 16 + b) * 128 + (size_t)sel * 64) * 1024
      : ((size_t)b * 128 + (size_t)dir * 64 + (size_t)sel * 32) * 1024;

  const int lane = tid & 63, wave = tid >> 6;
  const int sr = lane & 15, sq = lane >> 4;

  // A staging: wave w handles groups w and w+4 (16 rows each) for hi & lo
  const size_t aoff0 = (size_t)(n0 + wave * 16 + sr) * 1024 + sq * 8;
  const size_t aoff1 = (size_t)(n0 + (wave + 4) * 16 + sr) * 1024 + sq * 8;
  const ushort_t* aH0 = adjHi + aoff0;
  const ushort_t* aH1 = adjHi + aoff1;
  const ushort_t* aL0 = adjLo + aoff0;
  const ushort_t* aL1 = adjLo + aoff1;
  const int dA0 = wave * 512 + lane * 8;
  const int dA1 = (wave + 4) * 512 + lane * 8;

  // B staging
  const ushort_t* bSrc0;
  const ushort_t* bSrc1 = nullptr;
  ushort_t* bDst0;
  ushort_t* bDst1 = nullptr;
  if (EPI == 0) {
    // 4 groups; wave w -> group w, both planes
    const size_t bo = boff + (size_t)(wave * 16 + sr) * 1024 + sq * 8;
    bSrc0 = BtH + bo;  bDst0 = BhS + wave * 512 + lane * 8;
    bSrc1 = BtL + bo;  bDst1 = BlS + wave * 512 + lane * 8;
  } else {
    // 2 groups x 2 planes; waves 0,1 -> Bh g0,g1; waves 2,3 -> Bl g0,g1
    const int g = wave & 1;
    const size_t bo = boff + (size_t)(g * 16 + sr) * 1024 + sq * 8;
    bSrc0 = (wave < 2 ? BtH : BtL) + bo;
    bDst0 = (wave < 2 ? BhS : BlS) + g * 512 + lane * 8;
  }

  const int wr = (EPI == 0) ? (wave >> 1) * 64 : wave * 32;
  const int wc = (EPI == 0) ? (wave & 1) * 32 : 0;

  f32x4 acc[TI][TJ];
#pragma unroll
  for (int i = 0; i < TI; ++i)
#pragma unroll
    for (int j = 0; j < TJ; ++j) acc[i][j] = (f32x4)0.0f;

  for (int kt = 0; kt < 32; ++kt) {
    const int off = kt * 32;
    async16(aH0 + off, AhS + dA0);
    async16(aH1 + off, AhS + dA1);
    async16(aL0 + off, AlS + dA0);
    async16(aL1 + off, AlS + dA1);
    async16(bSrc0 + off, bDst0);
    if (EPI == 0) async16(bSrc1 + off, bDst1);
    __syncthreads();          // compiler drains vmcnt before barrier

    bf16x8 bf[TJ][2];
#pragma unroll
    for (int tj = 0; tj < TJ; ++tj) {
      const int o = foff(wc + tj * 16, lane);
      bf[tj][0] = ld16(BhS + o);
      bf[tj][1] = ld16(BlS + o);
    }
#pragma unroll
    for (int ti = 0; ti < TI; ++ti) {
      const int o = foff(wr + ti * 16, lane);
      bf16x8 ah = ld16(AhS + o);
      bf16x8 al = ld16(AlS + o);
#pragma unroll
      for (int tj = 0; tj < TJ; ++tj)
        acc[ti][tj] = mm3(ah, al, bf[tj][0], bf[tj][1], acc[ti][tj]);
    }
    __syncthreads();          // all reads done before next overwrite
  }

  const int lm = lane & 15;
  const int rq = (lane >> 4) * 4;
  const size_t rowbase = (size_t)b * 1024 + n0 + wr;

  if (EPI == 0) {
    float* zb = zbuf + (size_t)dir * ((size_t)ROWS * 64);
    float* rb = rhb  + (size_t)dir * ((size_t)ROWS * 64);
    const float* hb = dir ? h1 : h0;
    if (sel == 0) {                      // z gate
      const float* bz = dir ? c0R : c0F;
#pragma unroll
      for (int ti = 0; ti < TI; ++ti)
#pragma unroll
        for (int tj = 0; tj < TJ; ++tj) {
          const int c = wc + tj * 16 + lm;
          const float bv = bz[c];
#pragma unroll
          for (int r = 0; r < 4; ++r) {
            const size_t row = rowbase + ti * 16 + rq + r;
            zb[row * 64 + c] = sigmoidf_(acc[ti][tj][r] + bv);
          }
        }
    } else {                             // r gate -> rh
      const float* br = dir ? c1R : c1F;
#pragma unroll
      for (int ti = 0; ti < TI; ++ti)
#pragma unroll
        for (int tj = 0; tj < TJ; ++tj) {
          const int c = wc + tj * 16 + lm;
          const float bv = br[c];
#pragma unroll
          for (int r = 0; r < 4; ++r) {
            const size_t row = rowbase + ti * 16 + rq + r;
            const float rr = sigmoidf_(acc[ti][tj][r] + bv);
            rb[row * 64 + c] = rr * hb[row * 64 + c];
          }
        }
    }
  } else {
    const float* bc = dir ? c0R : c0F;
    const float* zb = zbuf + (size_t)dir * ((size_t)ROWS * 64);
    float* hb = dir ? h1 : h0;
#pragma unroll
    for (int ti = 0; ti < TI; ++ti)
#pragma unroll
      for (int tj = 0; tj < TJ; ++tj) {
        const int c = sel * 32 + tj * 16 + lm;
        const float bv = bc[c];
#pragma unroll
        for (int r = 0; r < 4; ++r) {
          const size_t row = rowbase + ti * 16 + rq + r;
          const size_t idx = row * 64 + c;
          const float cc = tanhf(acc[ti][tj][r] + bv);
          const float zv = zb[idx];
          const float hv = hb[idx];
          hb[idx] = zv * hv + (1.0f - zv) * cc;
        }
      }
  }
}

// ---------------------------------------------------------------------------
// dec1: D1[row][256] = relu(concat(hid_f,hid_r)[row] @ Wd1 + bd1)
// ---------------------------------------------------------------------------
__global__ __launch_bounds__(256) void dec1_mfma(
    const float* __restrict__ Hws,
    const ushort_t* __restrict__ WH, const ushort_t* __restrict__ WL,
    const float* __restrict__ bd1,
    float* __restrict__ D1)
{
  const int tid = threadIdx.x;
  const int row0 = blockIdx.x * 128;
  const int cb   = blockIdx.y * 128;
  const int l  = row0 >> 14;
  const int ri0 = row0 & 16383;
  const float* Hf = Hws + (size_t)l * HSZ;
  const float* Hr = Hws + (size_t)(2 + l) * HSZ;
  const ushort_t* BH = WH + WOFF_D1;
  const ushort_t* BL = WL + WOFF_D1;

  const int lane = tid & 63, wave = tid >> 6;
  const int wr = (wave >> 1) * 64, wc = (wave & 1) * 64;
  const int lm = lane & 15, q8 = (lane >> 4) * 8;

  f32x4 acc[4][4];
#pragma unroll
  for (int i = 0; i < 4; ++i)
#pragma unroll
    for (int j = 0; j < 4; ++j) acc[i][j] = (f32x4)0.0f;

#pragma unroll
  for (int kt = 0; kt < 4; ++kt) {
    const int k0 = kt * 32 + q8;
    bf16x8 bh[4], bl[4];
#pragma unroll
    for (int tj = 0; tj < 4; ++tj) {
      const size_t off = (size_t)(cb + wc + tj * 16 + lm) * 128 + k0;
      bh[tj] = ld16(BH + off);
      bl[tj] = ld16(BL + off);
    }
#pragma unroll
    for (int ti = 0; ti < 4; ++ti) {
      const int ri = ri0 + wr + ti * 16 + lm;
      const float* src = (k0 < 64) ? (Hf + (size_t)ri * 64 + k0)
                                   : (Hr + (size_t)ri * 64 + (k0 - 64));
      float a8[8];
      ld8f(src, a8);
      bf16x8 ah, al;
      split8(a8, ah, al);
#pragma unroll
      for (int tj = 0; tj < 4; ++tj) acc[ti][tj] = mm3(ah, al, bh[tj], bl[tj], acc[ti][tj]);
    }
  }

  const int rq = (lane >> 4) * 4;
#pragma unroll
  for (int ti = 0; ti < 4; ++ti)
#pragma unroll
    for (int tj = 0; tj < 4; ++tj) {
      const int col = cb + wc + tj * 16 + lm;
      const float bv = bd1[col];
#pragma unroll
      for (int r = 0; r < 4; ++r) {
        const size_t row = row0 + wr + ti * 16 + rq + r;
        D1[row * 256 + col] = fmaxf(acc[ti][tj][r] + bv, 0.0f);
      }
    }
}

// ---------------------------------------------------------------------------
// dec2: out[row][64] = D1[row] @ Wd2 + bd2.  Block 256 rows. Grid 128.
// ---------------------------------------------------------------------------
__global__ __launch_bounds__(256) void dec2_mfma(
    const float* __restrict__ D1,
    const ushort_t* __restrict__ WH, const ushort_t* __restrict__ WL,
    const float* __restrict__ bd2,
    float* __restrict__ out)
{
  const int tid = threadIdx.x;
  const int row0 = blockIdx.x * 256;
  const ushort_t* BH = WH + WOFF_D2;
  const ushort_t* BL = WL + WOFF_D2;

  const int lane = tid & 63, wave = tid >> 6;
  const int wr = wave * 64;
  const int lm = lane & 15, q8 = (lane >> 4) * 8;

  f32x4 acc[4][4];
#pragma unroll
  for (int i = 0; i < 4; ++i)
#pragma unroll
    for (int j = 0; j < 4; ++j) acc[i][j] = (f32x4)0.0f;

#pragma unroll
  for (int kt = 0; kt < 8; ++kt) {
    const int k0 = kt * 32 + q8;
    bf16x8 bh[4], bl[4];
#pragma unroll
    for (int tj = 0; tj < 4; ++tj) {
      const size_t off = (size_t)(tj * 16 + lm) * 256 + k0;
      bh[tj] = ld16(BH + off);
      bl[tj] = ld16(BL + off);
    }
#pragma unroll
    for (int ti = 0; ti < 4; ++ti) {
      const size_t row = row0 + wr + ti * 16 + lm;
      float a8[8];
      ld8f(D1 + row * 256 + k0, a8);
      bf16x8 ah, al;
      split8(a8, ah, al);
#pragma unroll
      for (int tj = 0; tj < 4; ++tj) acc[ti][tj] = mm3(ah, al, bh[tj], bl[tj], acc[ti][tj]);
    }
  }

  const int rq = (lane >> 4) * 4;
#pragma unroll
  for (int ti = 0; ti < 4; ++ti)
#pragma unroll
    for (int tj = 0; tj < 4; ++tj) {
      const int col = tj * 16 + lm;
      const float bv = bd2[col];
#pragma unroll
      for (int r = 0; r < 4; ++r) {
        const size_t row = row0 + wr + ti * 16 + rq + r;
        out[row * 64 + col] = acc[ti][tj][r] + bv;
      }
    }
}

// ---------------------------------------------------------------------------
// Host driver
// ---------------------------------------------------------------------------
extern "C" void kernel_launch(void* const* d_in, const int* in_sizes, int n_in,
                              void* d_out, int out_size, void* d_ws, size_t ws_size,
                              hipStream_t stream)
{
  (void)in_sizes; (void)n_in; (void)out_size; (void)ws_size;
  const float* inputs = (const float*)d_in[0];
  const float* mask   = (const float*)d_in[1];
  const float* adj    = (const float*)d_in[2];
  const float* Wp1    = (const float*)d_in[3];
  const float* bp1    = (const float*)d_in[4];
  const float* Wp2    = (const float*)d_in[5];
  const float* bp2    = (const float*)d_in[6];
  const float* Wz_f   = (const float*)d_in[7];
  const float* Wr_f   = (const float*)d_in[8];
  const float* Wc_f   = (const float*)d_in[9];
  const float* bz_f   = (const float*)d_in[10];
  const float* br_f   = (const float*)d_in[11];
  const float* bc_f   = (const float*)d_in[12];
  const float* Wz_r   = (const float*)d_in[13];
  const float* Wr_r   = (const float*)d_in[14];
  const float* Wc_r   = (const float*)d_in[15];
  const float* bz_r   = (const float*)d_in[16];
  const float* br_r   = (const float*)d_in[17];
  const float* bc_r   = (const float*)d_in[18];
  const float* Wd1    = (const float*)d_in[19];
  const float* bd1    = (const float*)d_in[20];
  const float* Wd2    = (const float*)d_in[21];
  const float* bd2    = (const float*)d_in[22];

  float* ws = (float*)d_ws;
  float* S0 = ws;                                   // TOT
  float* X  = S0 + TOT;                             // TOT*64
  float* H  = X + (size_t)TOT * 64;                 // 4*HSZ [dir*2+l]
  float* Z  = H + 4 * HSZ;                          // 2*HSZ
  float* RH = Z + 2 * HSZ;                          // 2*HSZ
  ushort_t* ADJH = (ushort_t*)(RH + 2 * HSZ);       // 1M ushorts
  ushort_t* ADJL = ADJH + (size_t)1024 * 1024;
  ushort_t* WH   = ADJL + (size_t)1024 * 1024;      // WTOT
  ushort_t* WL   = WH + WTOT;
  float* U = (float*)(WL + WTOT);                   // union region
  ushort_t* G1TH = (ushort_t*)U;
  ushort_t* G1TL = G1TH + (size_t)2 * 16 * 128 * 1024;
  ushort_t* G2TH = G1TL + (size_t)2 * 16 * 128 * 1024;
  ushort_t* G2TL = G2TH + (size_t)16 * 128 * 1024;
  float* D1 = U;                                    // aliases G after loop

  hipMemsetAsync(H, 0, 4 * HSZ * sizeof(float), stream);

  seq_kernel<<<dim3((HALF + 255) / 256), 256, 0, stream>>>(inputs, S0);
  wprep_kernel<<<dim3((WTOT + 255) / 256), 256, 0, stream>>>(
      Wz_f, Wr_f, Wc_f, Wz_r, Wr_r, Wc_r, Wp2, Wd1, Wd2, WH, WL);
  adjsplit_kernel<<<dim3(4096), 256, 0, stream>>>(adj, ADJH, ADJL);
  proj_mfma<<<dim3(TOT / 256), 256, 0, stream>>>(S0, mask, Wp1, bp1, bp2, WH, WL, X);

  for (int t = 0; t < Tn; ++t) {
    for (int l = 0; l < Ln; ++l) {
      const float* x0 = (l == 0) ? (X + (size_t)t * HSZ) : H;
      const float* x1 = (l == 0) ? (X + (size_t)(Tn - 1 - t) * HSZ) : (H + 2 * HSZ);
      float* h0 = H + (size_t)l * HSZ;
      float* h1 = H + (size_t)(2 + l) * HSZ;

      prez_mfma<<<dim3(128, 1, 2), 256, 0, stream>>>(
          x0, x1, h0, h1, WH, WL, l, G1TH, G1TL);
      conv_mfma<0><<<dim3(8, 16, 4), 256, 0, stream>>>(
          ADJH, ADJL, G1TH, G1TL,
          bz_f + l * 64, bz_r + l * 64, br_f + l * 64, br_r + l * 64,
          Z, RH, h0, h1);
      prec_mfma<<<dim3(128, 1, 2), 128, 0, stream>>>(
          x0, x1, RH, WH, WL, l, G2TH, G2TL);
      conv_mfma<1><<<dim3(8, 16, 4), 256, 0, stream>>>(
          ADJH, ADJL, G2TH, G2TL,
          bc_f + l * 64, bc_r + l * 64, bc_f + l * 64, bc_r + l * 64,
          Z, RH, h0, h1);
    }
  }

  dec1_mfma<<<dim3(256, 2), 256, 0, stream>>>(H, WH, WL, bd1, D1);
  dec2_mfma<<<dim3(128), 256, 0, stream>>>(D1, WH, WL, bd2, (float*)d_out);
}

// Round 7
// 2134.124 us; speedup vs baseline: 2.0575x; 1.4781x over previous
//
#include <hip/hip_runtime.h>
#include <cstdint>
#include <cstddef>

constexpr int Tn = 12, Bn = 16, Nn = 1024, Hn = 64, Ln = 2;
constexpr int ROWS = Bn * Nn;                 // 16384
constexpr int TOT  = Tn * Bn * Nn;            // 196608
constexpr int HALF = TOT / 2;
constexpr size_t HSZ = (size_t)Bn * Nn * Hn;  // 1048576 floats

#define DEVFN __device__ __forceinline__

typedef __attribute__((ext_vector_type(4))) float f32x4;
typedef __attribute__((ext_vector_type(4))) int   i32x4;
typedef __attribute__((ext_vector_type(8))) __bf16 bf16x8;
typedef unsigned short ushort_t;

// weight-plane offsets (in elements) inside WH/WL (bf16 path, non-conv GEMMs)
constexpr size_t WOFF_PZ = 0;        // [d][l][n:128][k:128]  prez B
constexpr size_t WOFF_PC = 65536;    // [d][l][n:64][k:128]   prec B
constexpr size_t WOFF_P2 = 98304;    // [n:64][k:256]         proj B (Wp2)
constexpr size_t WOFF_D1 = 114688;   // [n:256][k:128]        dec1 B (Wd1)
constexpr size_t WOFF_D2 = 147456;   // [n:64][k:256]         dec2 B (Wd2)
constexpr size_t WTOT    = 163840;

// ---------------------------------------------------------------------------
// bf16 split helpers (RNE) — for the non-conv GEMMs
// ---------------------------------------------------------------------------
DEVFN ushort_t f2bf_rne(float f) {
  uint32_t u = __float_as_uint(f);
  uint32_t r = u + 0x7FFFu + ((u >> 16) & 1u);
  return (ushort_t)(r >> 16);
}
DEVFN float bf2f(ushort_t h) { return __uint_as_float(((uint32_t)h) << 16); }

DEVFN void split8(const float* f, bf16x8& h8, bf16x8& l8) {
  alignas(16) ushort_t hs[8], ls[8];
#pragma unroll
  for (int j = 0; j < 8; ++j) {
    ushort_t h = f2bf_rne(f[j]);
    hs[j] = h;
    ls[j] = f2bf_rne(f[j] - bf2f(h));
  }
  h8 = *reinterpret_cast<bf16x8*>(hs);
  l8 = *reinterpret_cast<bf16x8*>(ls);
}

DEVFN f32x4 mm3(bf16x8 ah, bf16x8 al, bf16x8 bh, bf16x8 bl, f32x4 c) {
  c = __builtin_amdgcn_mfma_f32_16x16x32_bf16(ah, bh, c, 0, 0, 0);
  c = __builtin_amdgcn_mfma_f32_16x16x32_bf16(ah, bl, c, 0, 0, 0);
  c = __builtin_amdgcn_mfma_f32_16x16x32_bf16(al, bh, c, 0, 0, 0);
  return c;
}

DEVFN bf16x8 ld16(const ushort_t* p) { return *reinterpret_cast<const bf16x8*>(p); }

DEVFN void ld8f(const float* p, float* out) {
  float4 v0 = *reinterpret_cast<const float4*>(p);
  float4 v1 = *reinterpret_cast<const float4*>(p + 4);
  out[0] = v0.x; out[1] = v0.y; out[2] = v0.z; out[3] = v0.w;
  out[4] = v1.x; out[5] = v1.y; out[6] = v1.z; out[7] = v1.w;
}

// async global->LDS, 16B per lane (wave-uniform base; lane auto-offset x16)
DEVFN void async16(const void* g, void* l) {
  __builtin_amdgcn_global_load_lds(
      (const __attribute__((address_space(1))) uint32_t*)g,
      (__attribute__((address_space(3))) uint32_t*)l, 16, 0, 0);
}

// i8 fixed-point quantization: v -> (b1,b0) digits, scale 2^-12, range ~(-8,8)
DEVFN void quant_i8(float v, char& b1, char& b0) {
  int i = __float2int_rn(v * 4096.0f);
  i = max(-32768, min(32639, i));
  int d1 = (i + 128) >> 8;
  int d0 = i - (d1 << 8);
  b1 = (char)d1; b0 = (char)d0;
}

// ---------------------------------------------------------------------------
// threefry2x32 (key 0,42) + XLA-exact normal
// ---------------------------------------------------------------------------
DEVFN uint32_t rotl32(uint32_t v, int d) { return (v << d) | (v >> (32 - d)); }

DEVFN void threefry_0_42(uint32_t& x0, uint32_t& x1) {
  const uint32_t k0 = 0u, k1 = 42u, k2 = k0 ^ k1 ^ 0x1BD11BDAu;
  x0 += k0; x1 += k1;
#define TFR(r) { x0 += x1; x1 = rotl32(x1, r); x1 ^= x0; }
  TFR(13) TFR(15) TFR(26) TFR(6)
  x0 += k1; x1 += k2 + 1u;
  TFR(17) TFR(29) TFR(16) TFR(24)
  x0 += k2; x1 += k0 + 2u;
  TFR(13) TFR(15) TFR(26) TFR(6)
  x0 += k0; x1 += k1 + 3u;
  TFR(17) TFR(29) TFR(16) TFR(24)
  x0 += k1; x1 += k2 + 4u;
  TFR(13) TFR(15) TFR(26) TFR(6)
  x0 += k2; x1 += k0 + 5u;
#undef TFR
}

DEVFN float erfinv32(float x) {
  float w = -log1pf(-x * x);
  float p;
  if (w < 5.0f) {
    w = w - 2.5f;
    p = 2.81022636e-08f;
    p = fmaf(p, w, 3.43273939e-07f);
    p = fmaf(p, w, -3.5233877e-06f);
    p = fmaf(p, w, -4.39150654e-06f);
    p = fmaf(p, w, 0.00021858087f);
    p = fmaf(p, w, -0.00125372503f);
    p = fmaf(p, w, -0.00417768164f);
    p = fmaf(p, w, 0.246640727f);
    p = fmaf(p, w, 1.50140941f);
  } else {
    w = sqrtf(w) - 3.0f;
    p = -0.000200214257f;
    p = fmaf(p, w, 0.000100950558f);
    p = fmaf(p, w, 0.00134934322f);
    p = fmaf(p, w, -0.00367342844f);
    p = fmaf(p, w, 0.00573950773f);
    p = fmaf(p, w, -0.0076224613f);
    p = fmaf(p, w, 0.00943887047f);
    p = fmaf(p, w, 1.00167406f);
    p = fmaf(p, w, 2.83297682f);
  }
  return p * x;
}

DEVFN float bits_to_normal(uint32_t bits) {
  float f = __uint_as_float((bits >> 9) | 0x3f800000u) - 1.0f;
  const float lo = -0.99999994f;
  float u = fmaf(f, 2.0f, lo);
  u = fmaxf(lo, u);
  return 1.41421356237f * erfinv32(u);
}

__global__ __launch_bounds__(256) void seq_kernel(const float* __restrict__ inputs,
                                                  float* __restrict__ s0) {
  int i = blockIdx.x * 256 + threadIdx.x;
  if (i >= HALF) return;
  uint32_t x0 = (uint32_t)i, x1 = (uint32_t)(i + HALF);
  threefry_0_42(x0, x1);
  s0[i]        = inputs[i]        + 0.01f * bits_to_normal(x0);
  s0[i + HALF] = inputs[i + HALF] + 0.01f * bits_to_normal(x1);
}

DEVFN float sigmoidf_(float x) { return 1.0f / (1.0f + expf(-x)); }

// ---------------------------------------------------------------------------
// adj -> i8 digit planes: A = rn(adj*2^24) in [0,16384]; A1=(A+128)>>8, A0=A-256*A1
// ---------------------------------------------------------------------------
__global__ __launch_bounds__(256) void adjsplit_kernel(const float* __restrict__ adj,
                                                       char* __restrict__ d1,
                                                       char* __restrict__ d0) {
  int i = blockIdx.x * 256 + threadIdx.x;
  int A = __float2int_rn(adj[i] * 16777216.0f);
  int a1 = (A + 128) >> 8;
  int a0 = A - (a1 << 8);
  d1[i] = (char)a1;
  d0[i] = (char)a0;
}

// ---------------------------------------------------------------------------
// wprep: split + transpose all non-conv GEMM B-weights into [n][k] bf16 hi/lo
// ---------------------------------------------------------------------------
__global__ __launch_bounds__(256) void wprep_kernel(
    const float* __restrict__ WzF, const float* __restrict__ WrF, const float* __restrict__ WcF,
    const float* __restrict__ WzR, const float* __restrict__ WrR, const float* __restrict__ WcR,
    const float* __restrict__ Wp2, const float* __restrict__ Wd1, const float* __restrict__ Wd2,
    ushort_t* __restrict__ WH, ushort_t* __restrict__ WL)
{
  size_t i = (size_t)blockIdx.x * 256 + threadIdx.x;
  if (i >= WTOT) return;
  float v;
  if (i < WOFF_PC) {                          // PZ [d][l][n:128][k:128]
    int d = (i >> 15) & 1, l = (i >> 14) & 1, n = (i >> 7) & 127, k = i & 127;
    const float* W = (n < 64) ? (d ? WzR : WzF) : (d ? WrR : WrF);
    v = W[l * 8192 + k * 64 + (n & 63)];
  } else if (i < WOFF_P2) {                   // PC [d][l][n:64][k:128]
    size_t j = i - WOFF_PC;
    int d = (j >> 14) & 1, l = (j >> 13) & 1, n = (j >> 7) & 63, k = j & 127;
    const float* W = d ? WcR : WcF;
    v = W[l * 8192 + k * 64 + n];
  } else if (i < WOFF_D1) {                   // P2 [n:64][k:256]
    size_t j = i - WOFF_P2;
    int n = j >> 8, k = j & 255;
    v = Wp2[k * 64 + n];
  } else if (i < WOFF_D2) {                   // D1 [n:256][k:128]
    size_t j = i - WOFF_D1;
    int n = j >> 7, k = j & 127;
    v = Wd1[k * 256 + n];
  } else {                                    // D2 [n:64][k:256]
    size_t j = i - WOFF_D2;
    int n = j >> 8, k = j & 255;
    v = Wd2[k * 64 + n];
  }
  ushort_t h = f2bf_rne(v);
  WH[i] = h;
  WL[i] = f2bf_rne(v - bf2f(h));
}

// ---------------------------------------------------------------------------
// proj: X[m][64] = relu(s0*W0+s1*W1+bp1) @ Wp2 + bp2   (M=196608,N=64,K=256)
// ---------------------------------------------------------------------------
__global__ __launch_bounds__(256) void proj_mfma(
    const float* __restrict__ s0g, const float* __restrict__ s1g,
    const float* __restrict__ Wp1, const float* __restrict__ bp1,
    const float* __restrict__ bp2,
    const ushort_t* __restrict__ WH, const ushort_t* __restrict__ WL,
    float* __restrict__ X)
{
  __shared__ float W0[256], W1[256], Bb[256], SS0[256], SS1[256];
  const int tid = threadIdx.x;
  const int row0 = blockIdx.x * 256;
  W0[tid] = Wp1[tid];
  W1[tid] = Wp1[256 + tid];
  Bb[tid] = bp1[tid];
  SS0[tid] = s0g[row0 + tid];
  SS1[tid] = s1g[row0 + tid];
  __syncthreads();

  const int lane = tid & 63, wave = tid >> 6;
  const int lm = lane & 15, q8 = (lane >> 4) * 8;
  const ushort_t* P2H = WH + WOFF_P2;
  const ushort_t* P2L = WL + WOFF_P2;

  float sv0[4], sv1[4];
#pragma unroll
  for (int ti = 0; ti < 4; ++ti) {
    sv0[ti] = SS0[wave * 64 + ti * 16 + lm];
    sv1[ti] = SS1[wave * 64 + ti * 16 + lm];
  }

  f32x4 acc[4][4];
#pragma unroll
  for (int i = 0; i < 4; ++i)
#pragma unroll
    for (int j = 0; j < 4; ++j) acc[i][j] = (f32x4)0.0f;

  for (int kt = 0; kt < 8; ++kt) {
    const int kc = kt * 32 + q8;
    bf16x8 bh[4], bl[4];
#pragma unroll
    for (int tj = 0; tj < 4; ++tj) {
      bh[tj] = ld16(P2H + (size_t)(tj * 16 + lm) * 256 + kc);
      bl[tj] = ld16(P2L + (size_t)(tj * 16 + lm) * 256 + kc);
    }
    float w08[8], w18[8], bb8[8];
#pragma unroll
    for (int j = 0; j < 8; ++j) { w08[j] = W0[kc + j]; w18[j] = W1[kc + j]; bb8[j] = Bb[kc + j]; }
#pragma unroll
    for (int ti = 0; ti < 4; ++ti) {
      float a8[8];
#pragma unroll
      for (int j = 0; j < 8; ++j)
        a8[j] = fmaxf(fmaf(sv0[ti], w08[j], fmaf(sv1[ti], w18[j], bb8[j])), 0.0f);
      bf16x8 ah, al;
      split8(a8, ah, al);
#pragma unroll
      for (int tj = 0; tj < 4; ++tj) acc[ti][tj] = mm3(ah, al, bh[tj], bl[tj], acc[ti][tj]);
    }
  }

  const int rq = (lane >> 4) * 4;
  const int rowbase = row0 + wave * 64;
#pragma unroll
  for (int ti = 0; ti < 4; ++ti)
#pragma unroll
    for (int tj = 0; tj < 4; ++tj) {
      const int col = tj * 16 + lm;
      const float bv = bp2[col];
#pragma unroll
      for (int r = 0; r < 4; ++r)
        X[(size_t)(rowbase + ti * 16 + rq + r) * 64 + col] = acc[ti][tj][r] + bv;
    }
}

// ---------------------------------------------------------------------------
// prez: G1t[dir][b][c:128][m:1024] (i8 digit planes) = T(xh @ [Wz|Wr]) quantized
// ---------------------------------------------------------------------------
__global__ __launch_bounds__(256) void prez_mfma(
    const float* __restrict__ x0p, const float* __restrict__ x1p,
    const float* __restrict__ h0p, const float* __restrict__ h1p,
    const ushort_t* __restrict__ WH, const ushort_t* __restrict__ WL,
    int l,
    char* __restrict__ G1t1, char* __restrict__ G1t0)
{
  __shared__ float T[128][132];
  const int tid = threadIdx.x;
  const int row0 = blockIdx.x * 128;
  const int dir  = blockIdx.z;
  const int b    = row0 >> 10;
  const int nloc = row0 & 1023;
  const float* __restrict__ xs = dir ? x1p : x0p;
  const float* __restrict__ hs = dir ? h1p : h0p;
  const ushort_t* BH = WH + WOFF_PZ + (size_t)(dir * 2 + l) * 16384;
  const ushort_t* BL = WL + WOFF_PZ + (size_t)(dir * 2 + l) * 16384;

  const int lane = tid & 63, wave = tid >> 6;
  const int wr = (wave >> 1) * 64, wc = (wave & 1) * 64;
  const int lm = lane & 15, q8 = (lane >> 4) * 8;

  f32x4 acc[4][4];
#pragma unroll
  for (int i = 0; i < 4; ++i)
#pragma unroll
    for (int j = 0; j < 4; ++j) acc[i][j] = (f32x4)0.0f;

#pragma unroll
  for (int kt = 0; kt < 4; ++kt) {
    const int k0 = kt * 32 + q8;
    bf16x8 bh[4], bl[4];
#pragma unroll
    for (int tj = 0; tj < 4; ++tj) {
      const size_t off = (size_t)(wc + tj * 16 + lm) * 128 + k0;
      bh[tj] = ld16(BH + off);
      bl[tj] = ld16(BL + off);
    }
#pragma unroll
    for (int ti = 0; ti < 4; ++ti) {
      const int row = row0 + wr + ti * 16 + lm;
      const float* src = (k0 < 64) ? (xs + (size_t)row * 64 + k0)
                                   : (hs + (size_t)row * 64 + (k0 - 64));
      float a8[8];
      ld8f(src, a8);
      bf16x8 ah, al;
      split8(a8, ah, al);
#pragma unroll
      for (int tj = 0; tj < 4; ++tj) acc[ti][tj] = mm3(ah, al, bh[tj], bl[tj], acc[ti][tj]);
    }
  }

  const int rq = (lane >> 4) * 4;
#pragma unroll
  for (int ti = 0; ti < 4; ++ti)
#pragma unroll
    for (int tj = 0; tj < 4; ++tj)
#pragma unroll
      for (int r = 0; r < 4; ++r)
        T[wc + tj * 16 + lm][wr + ti * 16 + rq + r] = acc[ti][tj][r];
  __syncthreads();

  {
    const int c = tid >> 1, mc = (tid & 1) * 64;
    const size_t base = ((size_t)(dir * 16 + b) * 128 + c) * 1024 + nloc + mc;
#pragma unroll
    for (int q = 0; q < 4; ++q) {
      alignas(16) char q1[16], q0[16];
#pragma unroll
      for (int k = 0; k < 16; ++k)
        quant_i8(T[c][mc + q * 16 + k], q1[k], q0[k]);
      *reinterpret_cast<uint4*>(G1t1 + base + q * 16) = *reinterpret_cast<uint4*>(q1);
      *reinterpret_cast<uint4*>(G1t0 + base + q * 16) = *reinterpret_cast<uint4*>(q0);
    }
  }
}

// ---------------------------------------------------------------------------
// prec: G2t[b][dir*64+c][m:1024] (i8 digit planes) = T([x|r*h] @ Wc) quantized
// ---------------------------------------------------------------------------
__global__ __launch_bounds__(128) void prec_mfma(
    const float* __restrict__ x0p, const float* __restrict__ x1p,
    const float* __restrict__ rhbuf,
    const ushort_t* __restrict__ WH, const ushort_t* __restrict__ WL,
    int l,
    char* __restrict__ G2t1, char* __restrict__ G2t0)
{
  __shared__ float T[64][132];
  const int tid = threadIdx.x;
  const int row0 = blockIdx.x * 128;
  const int dir  = blockIdx.z;
  const int b    = row0 >> 10;
  const int nloc = row0 & 1023;
  const float* __restrict__ xs = dir ? x1p : x0p;
  const float* __restrict__ rs = rhbuf + (size_t)dir * ((size_t)ROWS * 64);
  const ushort_t* BH = WH + WOFF_PC + (size_t)(dir * 2 + l) * 8192;
  const ushort_t* BL = WL + WOFF_PC + (size_t)(dir * 2 + l) * 8192;

  const int lane = tid & 63, wave = tid >> 6;   // wave 0..1
  const int wr = wave * 64;
  const int lm = lane & 15, q8 = (lane >> 4) * 8;

  f32x4 acc[4][4];
#pragma unroll
  for (int i = 0; i < 4; ++i)
#pragma unroll
    for (int j = 0; j < 4; ++j) acc[i][j] = (f32x4)0.0f;

#pragma unroll
  for (int kt = 0; kt < 4; ++kt) {
    const int k0 = kt * 32 + q8;
    bf16x8 bh[4], bl[4];
#pragma unroll
    for (int tj = 0; tj < 4; ++tj) {
      const size_t off = (size_t)(tj * 16 + lm) * 128 + k0;
      bh[tj] = ld16(BH + off);
      bl[tj] = ld16(BL + off);
    }
#pragma unroll
    for (int ti = 0; ti < 4; ++ti) {
      const int row = row0 + wr + ti * 16 + lm;
      const float* src = (k0 < 64) ? (xs + (size_t)row * 64 + k0)
                                   : (rs + (size_t)row * 64 + (k0 - 64));
      float a8[8];
      ld8f(src, a8);
      bf16x8 ah, al;
      split8(a8, ah, al);
#pragma unroll
      for (int tj = 0; tj < 4; ++tj) acc[ti][tj] = mm3(ah, al, bh[tj], bl[tj], acc[ti][tj]);
    }
  }

  const int rq = (lane >> 4) * 4;
#pragma unroll
  for (int ti = 0; ti < 4; ++ti)
#pragma unroll
    for (int tj = 0; tj < 4; ++tj)
#pragma unroll
      for (int r = 0; r < 4; ++r)
        T[tj * 16 + lm][wr + ti * 16 + rq + r] = acc[ti][tj][r];
  __syncthreads();

  {
    const int c = tid >> 1, mc = (tid & 1) * 64;
    const size_t base = ((size_t)b * 128 + (size_t)dir * 64 + c) * 1024 + nloc + mc;
#pragma unroll
    for (int q = 0; q < 4; ++q) {
      alignas(16) char q1[16], q0[16];
#pragma unroll
      for (int k = 0; k < 16; ++k)
        quant_i8(T[c][mc + q * 16 + k], q1[k], q0[k]);
      *reinterpret_cast<uint4*>(G2t1 + base + q * 16) = *reinterpret_cast<uint4*>(q1);
      *reinterpret_cast<uint4*>(G2t0 + base + q * 16) = *reinterpret_cast<uint4*>(q0);
    }
  }
}

// ---------------------------------------------------------------------------
// conv_mfma (i8 fixed point): AG = adj @ G via mfma_i32_16x16x64_i8.
// result = acc1*2^-20 + accm*2^-28 (Sa=2^-24, Sb=2^-12).
// EPI=0: tile 128n x 64c, grid (8,16,4) z = dir*2 + gate-half (0:z, 1:r)
// EPI=1: tile 128n x 32c, grid (8,16,4) z = dir*2 + col-half within dir
// 256 thr. LDS double-buffered; layout per plane: [group=row>>4][lane*16B].
// ---------------------------------------------------------------------------
template<int EPI>
__global__ __launch_bounds__(256) void conv_mfma(
    const char* __restrict__ adj1, const char* __restrict__ adj0,
    const char* __restrict__ Bt1,  const char* __restrict__ Bt0,
    const float* __restrict__ c0F, const float* __restrict__ c0R,
    const float* __restrict__ c1F, const float* __restrict__ c1R,
    float* __restrict__ zbuf, float* __restrict__ rhb,
    float* __restrict__ h0, float* __restrict__ h1)
{
  constexpr int TI = 4;
  constexpr int TJ = (EPI == 0) ? 2 : 1;
  constexpr int NBG = (EPI == 0) ? 4 : 2;          // B col groups (16 cols each)
  constexpr int BOFF_LDS = 16384;                  // A region: 8 groups x 2 planes
  constexpr int BUFSZ = BOFF_LDS + NBG * 1024 * 2;

  __shared__ __align__(16) char LB[2][BUFSZ];

  const int tid = threadIdx.x;
  const int n0  = blockIdx.x * 128;
  const int b   = blockIdx.y;
  const int z   = blockIdx.z;
  const int dir = z >> 1, sel = z & 1;

  const size_t boff = (EPI == 0)
      ? ((size_t)(dir * 16 + b) * 128 + (size_t)sel * 64) * 1024
      : ((size_t)b * 128 + (size_t)dir * 64 + (size_t)sel * 32) * 1024;

  const int lane = tid & 63, wave = tid >> 6;
  const int sr = lane & 15, sq = lane >> 4;

  // staging sources (advance 64 B per K-iter)
  const char* sA1a = adj1 + (size_t)(n0 + wave * 16 + sr) * 1024 + sq * 16;
  const char* sA1b = adj1 + (size_t)(n0 + (wave + 4) * 16 + sr) * 1024 + sq * 16;
  const char* sA0a = adj0 + (size_t)(n0 + wave * 16 + sr) * 1024 + sq * 16;
  const char* sA0b = adj0 + (size_t)(n0 + (wave + 4) * 16 + sr) * 1024 + sq * 16;
  const int dA1a = wave * 1024 + lane * 16;
  const int dA1b = (wave + 4) * 1024 + lane * 16;
  const int dA0a = 8192 + dA1a;
  const int dA0b = 8192 + dA1b;

  const char* sB1 = nullptr; int dB1 = 0;
  const char* sB0 = nullptr; int dB0 = 0;
  if (EPI == 0) {
    sB1 = Bt1 + boff + (size_t)(wave * 16 + sr) * 1024 + sq * 16;
    dB1 = BOFF_LDS + wave * 1024 + lane * 16;
    sB0 = Bt0 + boff + (size_t)(wave * 16 + sr) * 1024 + sq * 16;
    dB0 = BOFF_LDS + 4096 + wave * 1024 + lane * 16;
  } else {
    const int g = wave & 1;
    const char* plane = (wave < 2) ? Bt1 : Bt0;
    sB1 = plane + boff + (size_t)(g * 16 + sr) * 1024 + sq * 16;
    dB1 = BOFF_LDS + (wave < 2 ? 0 : 2048) + g * 1024 + lane * 16;
  }

  const int wr = (wave >> 1) * 64;
  const int wc = (EPI == 0) ? (wave & 1) * 32 : (wave & 1) * 16;

  i32x4 acc1[TI][TJ], accm[TI][TJ];
#pragma unroll
  for (int i = 0; i < TI; ++i)
#pragma unroll
    for (int j = 0; j < TJ; ++j) { acc1[i][j] = (i32x4)0; accm[i][j] = (i32x4)0; }

#define STAGE(bufi, kt)                                    \
  {                                                        \
    const int _o = (kt) * 64;                              \
    char* _L = LB[bufi];                                   \
    async16(sA1a + _o, _L + dA1a);                         \
    async16(sA1b + _o, _L + dA1b);                         \
    async16(sA0a + _o, _L + dA0a);                         \
    async16(sA0b + _o, _L + dA0b);                         \
    async16(sB1 + _o, _L + dB1);                           \
    if (EPI == 0) async16(sB0 + _o, _L + dB0);             \
  }

  STAGE(0, 0)
  for (int kt = 0; kt < 16; ++kt) {
    __syncthreads();                       // drains DMA for buf[kt&1]; fences prior reads
    if (kt + 1 < 16) STAGE((kt + 1) & 1, kt + 1)
    const char* L = LB[kt & 1];

    i32x4 b1f[TJ], b0f[TJ];
#pragma unroll
    for (int tj = 0; tj < TJ; ++tj) {
      const int o = BOFF_LDS + ((wc + tj * 16) >> 4) * 1024 + lane * 16;
      b1f[tj] = *reinterpret_cast<const i32x4*>(L + o);
      b0f[tj] = *reinterpret_cast<const i32x4*>(L + o + NBG * 1024);
    }
#pragma unroll
    for (int ti = 0; ti < TI; ++ti) {
      const int o = ((wr + ti * 16) >> 4) * 1024 + lane * 16;
      i32x4 a1 = *reinterpret_cast<const i32x4*>(L + o);
      i32x4 a0 = *reinterpret_cast<const i32x4*>(L + 8192 + o);
#pragma unroll
      for (int tj = 0; tj < TJ; ++tj) {
        acc1[ti][tj] = __builtin_amdgcn_mfma_i32_16x16x64_i8(a1, b1f[tj], acc1[ti][tj], 0, 0, 0);
        accm[ti][tj] = __builtin_amdgcn_mfma_i32_16x16x64_i8(a1, b0f[tj], accm[ti][tj], 0, 0, 0);
        accm[ti][tj] = __builtin_amdgcn_mfma_i32_16x16x64_i8(a0, b1f[tj], accm[ti][tj], 0, 0, 0);
      }
    }
  }
#undef STAGE

  const int lm = lane & 15;
  const int rq = (lane >> 4) * 4;
  const size_t rowbase = (size_t)b * 1024 + n0 + wr;
  const float S1 = 0x1p-20f, Sm = 0x1p-28f;

  if (EPI == 0) {
    float* zb = zbuf + (size_t)dir * ((size_t)ROWS * 64);
    float* rb = rhb  + (size_t)dir * ((size_t)ROWS * 64);
    const float* hb = dir ? h1 : h0;
    if (sel == 0) {                      // z gate
      const float* bz = dir ? c0R : c0F;
#pragma unroll
      for (int ti = 0; ti < TI; ++ti)
#pragma unroll
        for (int tj = 0; tj < TJ; ++tj) {
          const int c = wc + tj * 16 + lm;
          const float bv = bz[c];
#pragma unroll
          for (int r = 0; r < 4; ++r) {
            const size_t row = rowbase + ti * 16 + rq + r;
            const float v = (float)acc1[ti][tj][r] * S1 + (float)accm[ti][tj][r] * Sm + bv;
            zb[row * 64 + c] = sigmoidf_(v);
          }
        }
    } else {                             // r gate -> rh
      const float* br = dir ? c1R : c1F;
#pragma unroll
      for (int ti = 0; ti < TI; ++ti)
#pragma unroll
        for (int tj = 0; tj < TJ; ++tj) {
          const int c = wc + tj * 16 + lm;
          const float bv = br[c];
#pragma unroll
          for (int r = 0; r < 4; ++r) {
            const size_t row = rowbase + ti * 16 + rq + r;
            const float v = (float)acc1[ti][tj][r] * S1 + (float)accm[ti][tj][r] * Sm + bv;
            rb[row * 64 + c] = sigmoidf_(v) * hb[row * 64 + c];
          }
        }
    }
  } else {
    const float* bc = dir ? c0R : c0F;
    const float* zb = zbuf + (size_t)dir * ((size_t)ROWS * 64);
    float* hb = dir ? h1 : h0;
#pragma unroll
    for (int ti = 0; ti < TI; ++ti)
#pragma unroll
      for (int tj = 0; tj < TJ; ++tj) {
        const int c = sel * 32 + wc + tj * 16 + lm;
        const float bv = bc[c];
#pragma unroll
        for (int r = 0; r < 4; ++r) {
          const size_t row = rowbase + ti * 16 + rq + r;
          const size_t idx = row * 64 + c;
          const float v = (float)acc1[ti][tj][r] * S1 + (float)accm[ti][tj][r] * Sm + bv;
          const float cc = tanhf(v);
          const float zv = zb[idx];
          const float hv = hb[idx];
          hb[idx] = zv * hv + (1.0f - zv) * cc;
        }
      }
  }
}

// ---------------------------------------------------------------------------
// dec1: D1[row][256] = relu(concat(hid_f,hid_r)[row] @ Wd1 + bd1)
// ---------------------------------------------------------------------------
__global__ __launch_bounds__(256) void dec1_mfma(
    const float* __restrict__ Hws,
    const ushort_t* __restrict__ WH, const ushort_t* __restrict__ WL,
    const float* __restrict__ bd1,
    float* __restrict__ D1)
{
  const int tid = threadIdx.x;
  const int row0 = blockIdx.x * 128;
  const int cb   = blockIdx.y * 128;
  const int l  = row0 >> 14;
  const int ri0 = row0 & 16383;
  const float* Hf = Hws + (size_t)l * HSZ;
  const float* Hr = Hws + (size_t)(2 + l) * HSZ;
  const ushort_t* BH = WH + WOFF_D1;
  const ushort_t* BL = WL + WOFF_D1;

  const int lane = tid & 63, wave = tid >> 6;
  const int wr = (wave >> 1) * 64, wc = (wave & 1) * 64;
  const int lm = lane & 15, q8 = (lane >> 4) * 8;

  f32x4 acc[4][4];
#pragma unroll
  for (int i = 0; i < 4; ++i)
#pragma unroll
    for (int j = 0; j < 4; ++j) acc[i][j] = (f32x4)0.0f;

#pragma unroll
  for (int kt = 0; kt < 4; ++kt) {
    const int k0 = kt * 32 + q8;
    bf16x8 bh[4], bl[4];
#pragma unroll
    for (int tj = 0; tj < 4; ++tj) {
      const size_t off = (size_t)(cb + wc + tj * 16 + lm) * 128 + k0;
      bh[tj] = ld16(BH + off);
      bl[tj] = ld16(BL + off);
    }
#pragma unroll
    for (int ti = 0; ti < 4; ++ti) {
      const int ri = ri0 + wr + ti * 16 + lm;
      const float* src = (k0 < 64) ? (Hf + (size_t)ri * 64 + k0)
                                   : (Hr + (size_t)ri * 64 + (k0 - 64));
      float a8[8];
      ld8f(src, a8);
      bf16x8 ah, al;
      split8(a8, ah, al);
#pragma unroll
      for (int tj = 0; tj < 4; ++tj) acc[ti][tj] = mm3(ah, al, bh[tj], bl[tj], acc[ti][tj]);
    }
  }

  const int rq = (lane >> 4) * 4;
#pragma unroll
  for (int ti = 0; ti < 4; ++ti)
#pragma unroll
    for (int tj = 0; tj < 4; ++tj) {
      const int col = cb + wc + tj * 16 + lm;
      const float bv = bd1[col];
#pragma unroll
      for (int r = 0; r < 4; ++r) {
        const size_t row = row0 + wr + ti * 16 + rq + r;
        D1[row * 256 + col] = fmaxf(acc[ti][tj][r] + bv, 0.0f);
      }
    }
}

// ---------------------------------------------------------------------------
// dec2: out[row][64] = D1[row] @ Wd2 + bd2.  Block 256 rows. Grid 128.
// ---------------------------------------------------------------------------
__global__ __launch_bounds__(256) void dec2_mfma(
    const float* __restrict__ D1,
    const ushort_t* __restrict__ WH, const ushort_t* __restrict__ WL,
    const float* __restrict__ bd2,
    float* __restrict__ out)
{
  const int tid = threadIdx.x;
  const int row0 = blockIdx.x * 256;
  const ushort_t* BH = WH + WOFF_D2;
  const ushort_t* BL = WL + WOFF_D2;

  const int lane = tid & 63, wave = tid >> 6;
  const int wr = wave * 64;
  const int lm = lane & 15, q8 = (lane >> 4) * 8;

  f32x4 acc[4][4];
#pragma unroll
  for (int i = 0; i < 4; ++i)
#pragma unroll
    for (int j = 0; j < 4; ++j) acc[i][j] = (f32x4)0.0f;

#pragma unroll
  for (int kt = 0; kt < 8; ++kt) {
    const int k0 = kt * 32 + q8;
    bf16x8 bh[4], bl[4];
#pragma unroll
    for (int tj = 0; tj < 4; ++tj) {
      const size_t off = (size_t)(tj * 16 + lm) * 256 + k0;
      bh[tj] = ld16(BH + off);
      bl[tj] = ld16(BL + off);
    }
#pragma unroll
    for (int ti = 0; ti < 4; ++ti) {
      const size_t row = row0 + wr + ti * 16 + lm;
      float a8[8];
      ld8f(D1 + row * 256 + k0, a8);
      bf16x8 ah, al;
      split8(a8, ah, al);
#pragma unroll
      for (int tj = 0; tj < 4; ++tj) acc[ti][tj] = mm3(ah, al, bh[tj], bl[tj], acc[ti][tj]);
    }
  }

  const int rq = (lane >> 4) * 4;
#pragma unroll
  for (int ti = 0; ti < 4; ++ti)
#pragma unroll
    for (int tj = 0; tj < 4; ++tj) {
      const int col = tj * 16 + lm;
      const float bv = bd2[col];
#pragma unroll
      for (int r = 0; r < 4; ++r) {
        const size_t row = row0 + wr + ti * 16 + rq + r;
        out[row * 64 + col] = acc[ti][tj][r] + bv;
      }
    }
}

// ---------------------------------------------------------------------------
// Host driver
// ---------------------------------------------------------------------------
extern "C" void kernel_launch(void* const* d_in, const int* in_sizes, int n_in,
                              void* d_out, int out_size, void* d_ws, size_t ws_size,
                              hipStream_t stream)
{
  (void)in_sizes; (void)n_in; (void)out_size; (void)ws_size;
  const float* inputs = (const float*)d_in[0];
  const float* mask   = (const float*)d_in[1];
  const float* adj    = (const float*)d_in[2];
  const float* Wp1    = (const float*)d_in[3];
  const float* bp1    = (const float*)d_in[4];
  const float* Wp2    = (const float*)d_in[5];
  const float* bp2    = (const float*)d_in[6];
  const float* Wz_f   = (const float*)d_in[7];
  const float* Wr_f   = (const float*)d_in[8];
  const float* Wc_f   = (const float*)d_in[9];
  const float* bz_f   = (const float*)d_in[10];
  const float* br_f   = (const float*)d_in[11];
  const float* bc_f   = (const float*)d_in[12];
  const float* Wz_r   = (const float*)d_in[13];
  const float* Wr_r   = (const float*)d_in[14];
  const float* Wc_r   = (const float*)d_in[15];
  const float* bz_r   = (const float*)d_in[16];
  const float* br_r   = (const float*)d_in[17];
  const float* bc_r   = (const float*)d_in[18];
  const float* Wd1    = (const float*)d_in[19];
  const float* bd1    = (const float*)d_in[20];
  const float* Wd2    = (const float*)d_in[21];
  const float* bd2    = (const float*)d_in[22];

  float* ws = (float*)d_ws;
  float* S0 = ws;                                   // TOT
  float* X  = S0 + TOT;                             // TOT*64
  float* H  = X + (size_t)TOT * 64;                 // 4*HSZ [dir*2+l]
  float* Z  = H + 4 * HSZ;                          // 2*HSZ
  float* RH = Z + 2 * HSZ;                          // 2*HSZ
  char* ADJ1 = (char*)(RH + 2 * HSZ);               // 1 MB
  char* ADJ0 = ADJ1 + (size_t)1048576;              // 1 MB
  ushort_t* WH = (ushort_t*)(ADJ0 + (size_t)1048576);
  ushort_t* WL = WH + WTOT;
  char* U = (char*)(WL + WTOT);                     // union region
  char* G1T1 = U;                                   // 4 MB
  char* G1T0 = G1T1 + (size_t)4194304;              // 4 MB
  char* G2T1 = G1T0 + (size_t)4194304;              // 2 MB
  char* G2T0 = G2T1 + (size_t)2097152;              // 2 MB
  float* D1 = (float*)U;                            // 32 MB (aliases G after loop)

  hipMemsetAsync(H, 0, 4 * HSZ * sizeof(float), stream);

  seq_kernel<<<dim3((HALF + 255) / 256), 256, 0, stream>>>(inputs, S0);
  wprep_kernel<<<dim3((WTOT + 255) / 256), 256, 0, stream>>>(
      Wz_f, Wr_f, Wc_f, Wz_r, Wr_r, Wc_r, Wp2, Wd1, Wd2, WH, WL);
  adjsplit_kernel<<<dim3(4096), 256, 0, stream>>>(adj, ADJ1, ADJ0);
  proj_mfma<<<dim3(TOT / 256), 256, 0, stream>>>(S0, mask, Wp1, bp1, bp2, WH, WL, X);

  for (int t = 0; t < Tn; ++t) {
    for (int l = 0; l < Ln; ++l) {
      const float* x0 = (l == 0) ? (X + (size_t)t * HSZ) : H;
      const float* x1 = (l == 0) ? (X + (size_t)(Tn - 1 - t) * HSZ) : (H + 2 * HSZ);
      float* h0 = H + (size_t)l * HSZ;
      float* h1 = H + (size_t)(2 + l) * HSZ;

      prez_mfma<<<dim3(128, 1, 2), 256, 0, stream>>>(
          x0, x1, h0, h1, WH, WL, l, G1T1, G1T0);
      conv_mfma<0><<<dim3(8, 16, 4), 256, 0, stream>>>(
          ADJ1, ADJ0, G1T1, G1T0,
          bz_f + l * 64, bz_r + l * 64, br_f + l * 64, br_r + l * 64,
          Z, RH, h0, h1);
      prec_mfma<<<dim3(128, 1, 2), 128, 0, stream>>>(
          x0, x1, RH, WH, WL, l, G2T1, G2T0);
      conv_mfma<1><<<dim3(8, 16, 4), 256, 0, stream>>>(
          ADJ1, ADJ0, G2T1, G2T0,
          bc_f + l * 64, bc_r + l * 64, bc_f + l * 64, bc_r + l * 64,
          Z, RH, h0, h1);
    }
  }

  dec1_mfma<<<dim3(256, 2), 256, 0, stream>>>(H, WH, WL, bd1, D1);
  dec2_mfma<<<dim3(128), 256, 0, stream>>>(D1, WH, WL, bd2, (float*)d_out);
}